// Round 11
// baseline (562.622 us; speedup 1.0000x reference)
//
#include <hip/hip_runtime.h>
#include <hip/hip_fp16.h>

// GIN: h1 = relu((scatter_add(x) + (1+eps0)*x) @ W0^T)
//      h2 = relu((scatter_add(h1) + (1+eps1)*h1) @ W1^T)
//      out = (h1 @ Wm^T + h2) / 2
//
// R11: node-per-group gather. R10 counters (VALU 29%, HBM 19%, occ 41%)
// showed latency-bound with ONE node in flight per wave. Now each 8-lane
// group owns one node (8 lanes x uint4 fp16 = full 64-ch row):
//  - 8 independent gather chains per wave (8x MLP), NO cross-group reduce
//  - loop = wave-max degree, masked edges clamp idx->0 (bucket has slack)
//  - matvec amortizes W 8x with NAMED accumulators (R7 idea; R8 failed
//    because its gathers were serial -- these are parallel)
//  - dual accumulator sets halve fp16 chain depth (absmax hedge)
//  - grid 784: nearly all waves do exactly 2 octets (balanced)
// CSR build (rank-hist + atomic-free fill) and tiers B/C unchanged.

// ================================================================ CSR build
__global__ __launch_bounds__(256) void zero_int_kernel(int* __restrict__ p, int n)
{
    int i = blockIdx.x * blockDim.x + threadIdx.x;
    int stride = gridDim.x * blockDim.x;
    for (; i < n; i += stride) p[i] = 0;
}

__global__ __launch_bounds__(256) void hist_rank_kernel(
    const int* __restrict__ dst, int* __restrict__ deg,
    int* __restrict__ rank, int E)
{
    int base = (blockIdx.x * blockDim.x + threadIdx.x) * 16;
    if (base + 15 < E) {
        int4 a = *(const int4*)&dst[base];
        int4 b = *(const int4*)&dst[base + 4];
        int4 c = *(const int4*)&dst[base + 8];
        int4 d = *(const int4*)&dst[base + 12];
        int r0 = atomicAdd(&deg[a.x], 1);
        int r1 = atomicAdd(&deg[a.y], 1);
        int r2 = atomicAdd(&deg[a.z], 1);
        int r3 = atomicAdd(&deg[a.w], 1);
        int r4 = atomicAdd(&deg[b.x], 1);
        int r5 = atomicAdd(&deg[b.y], 1);
        int r6 = atomicAdd(&deg[b.z], 1);
        int r7 = atomicAdd(&deg[b.w], 1);
        int r8 = atomicAdd(&deg[c.x], 1);
        int r9 = atomicAdd(&deg[c.y], 1);
        int rA = atomicAdd(&deg[c.z], 1);
        int rB = atomicAdd(&deg[c.w], 1);
        int rC = atomicAdd(&deg[d.x], 1);
        int rD = atomicAdd(&deg[d.y], 1);
        int rE = atomicAdd(&deg[d.z], 1);
        int rF = atomicAdd(&deg[d.w], 1);
        *(int4*)&rank[base]      = make_int4(r0, r1, r2, r3);
        *(int4*)&rank[base + 4]  = make_int4(r4, r5, r6, r7);
        *(int4*)&rank[base + 8]  = make_int4(r8, r9, rA, rB);
        *(int4*)&rank[base + 12] = make_int4(rC, rD, rE, rF);
    } else {
        for (int e = base; e < E; ++e) rank[e] = atomicAdd(&deg[dst[e]], 1);
    }
}

__global__ __launch_bounds__(256) void hist_kernel(
    const int* __restrict__ dst, int* __restrict__ deg, int E)
{
    int e4 = (blockIdx.x * blockDim.x + threadIdx.x) * 4;
    if (e4 + 3 < E) {
        int4 d = *(const int4*)&dst[e4];
        atomicAdd(&deg[d.x], 1);
        atomicAdd(&deg[d.y], 1);
        atomicAdd(&deg[d.z], 1);
        atomicAdd(&deg[d.w], 1);
    } else {
        for (int e = e4; e < E; ++e) atomicAdd(&deg[dst[e]], 1);
    }
}

__global__ __launch_bounds__(256) void scanA_kernel(
    const int* __restrict__ deg, int* __restrict__ off,
    int* __restrict__ bsum, int n)
{
    __shared__ int tmp[256];
    int t = threadIdx.x;
    int base = blockIdx.x * 1024 + t * 4;
    int v0 = 0, v1 = 0, v2 = 0, v3 = 0;
    if (base + 3 < n) {
        int4 q = *(const int4*)&deg[base];
        v0 = q.x; v1 = q.y; v2 = q.z; v3 = q.w;
    } else {
        if (base + 0 < n) v0 = deg[base + 0];
        if (base + 1 < n) v1 = deg[base + 1];
        if (base + 2 < n) v2 = deg[base + 2];
    }
    int tot = v0 + v1 + v2 + v3;
    tmp[t] = tot;
    __syncthreads();
    for (int d = 1; d < 256; d <<= 1) {
        int x = (t >= d) ? tmp[t - d] : 0;
        __syncthreads();
        tmp[t] += x;
        __syncthreads();
    }
    int incl = tmp[t];
    int p = incl - tot;
    if (base + 0 < n) off[base + 0] = p;
    if (base + 1 < n) off[base + 1] = p + v0;
    if (base + 2 < n) off[base + 2] = p + v0 + v1;
    if (base + 3 < n) off[base + 3] = p + v0 + v1 + v2;
    if (t == 255) bsum[blockIdx.x] = incl;
}

__global__ __launch_bounds__(256) void scanB_kernel(int* __restrict__ bsum, int nb)
{
    __shared__ int tmp[256];
    int t = threadIdx.x;
    int v = (t < nb) ? bsum[t] : 0;
    tmp[t] = v;
    __syncthreads();
    for (int d = 1; d < 256; d <<= 1) {
        int x = (t >= d) ? tmp[t - d] : 0;
        __syncthreads();
        tmp[t] += x;
        __syncthreads();
    }
    if (t < nb) bsum[t] = tmp[t] - v;
}

__global__ __launch_bounds__(256) void scanC_kernel(
    int* __restrict__ off, int* __restrict__ cursor,
    const int* __restrict__ bsum, int n, int E)
{
    int t = threadIdx.x;
    int add = bsum[blockIdx.x];
    int base = blockIdx.x * 1024 + t * 4;
#pragma unroll
    for (int q = 0; q < 4; ++q) {
        int idx = base + q;
        if (idx < n) {
            int v = off[idx] + add;
            off[idx] = v;
            if (cursor) cursor[idx] = v;
        }
    }
    if (blockIdx.x == 0 && t == 0) off[n] = E;
}

__global__ __launch_bounds__(256) void fill_rank_kernel(
    const int* __restrict__ src, const int* __restrict__ dst,
    const int* __restrict__ rank, const int* __restrict__ off,
    int* __restrict__ bucket, int E)
{
    int base = (blockIdx.x * blockDim.x + threadIdx.x) * 8;
    if (base + 7 < E) {
        int4 d0 = *(const int4*)&dst[base];
        int4 d1 = *(const int4*)&dst[base + 4];
        int4 r0 = *(const int4*)&rank[base];
        int4 r1 = *(const int4*)&rank[base + 4];
        int4 s0 = *(const int4*)&src[base];
        int4 s1 = *(const int4*)&src[base + 4];
        bucket[off[d0.x] + r0.x] = s0.x;
        bucket[off[d0.y] + r0.y] = s0.y;
        bucket[off[d0.z] + r0.z] = s0.z;
        bucket[off[d0.w] + r0.w] = s0.w;
        bucket[off[d1.x] + r1.x] = s1.x;
        bucket[off[d1.y] + r1.y] = s1.y;
        bucket[off[d1.z] + r1.z] = s1.z;
        bucket[off[d1.w] + r1.w] = s1.w;
    } else {
        for (int e = base; e < E; ++e) bucket[off[dst[e]] + rank[e]] = src[e];
    }
}

__global__ __launch_bounds__(256) void fill_kernel(
    const int* __restrict__ src, const int* __restrict__ dst,
    int* __restrict__ cursor, int* __restrict__ bucket, int E)
{
    int e = blockIdx.x * blockDim.x + threadIdx.x;
    if (e < E) {
        int d = dst[e];
        int p = atomicAdd(&cursor[d], 1);
        bucket[p] = src[e];
    }
}

// ================================================================ fp32 -> fp16 convert
__global__ __launch_bounds__(256) void f32_to_f16_kernel(
    const float* __restrict__ in, __half* __restrict__ out, int total4)
{
    int i = blockIdx.x * blockDim.x + threadIdx.x;
    int stride = gridDim.x * blockDim.x;
    const float4* in4 = (const float4*)in;
    uint2* out4 = (uint2*)out;
    for (; i < total4; i += stride) {
        float4 v = in4[i];
        __half2 a = __floats2half2_rn(v.x, v.y);
        __half2 b = __floats2half2_rn(v.z, v.w);
        uint2 u;
        u.x = __builtin_bit_cast(unsigned int, a);
        u.y = __builtin_bit_cast(unsigned int, b);
        out4[i] = u;
    }
}

// ================================================================ helpers
#define WPB 8  // waves per 512-thread block

__device__ __forceinline__ __half2 bc_h2(unsigned int u)
{
    return __builtin_bit_cast(__half2, u);
}
__device__ __forceinline__ unsigned int bc_u(__half2 h)
{
    return __builtin_bit_cast(unsigned int, h);
}

#if __has_builtin(__builtin_amdgcn_fdot2)
typedef _Float16 half2_v __attribute__((ext_vector_type(2)));
__device__ __forceinline__ float fdot2(unsigned int a, unsigned int b, float c)
{
    return __builtin_amdgcn_fdot2(__builtin_bit_cast(half2_v, a),
                                  __builtin_bit_cast(half2_v, b), c, false);
}
#else
__device__ __forceinline__ float fdot2(unsigned int a, unsigned int b, float c)
{
    float2 af = __half22float2(bc_h2(a));
    float2 bf = __half22float2(bc_h2(b));
    return fmaf(af.x, bf.x, fmaf(af.y, bf.y, c));
}
#endif

// ================================================================ tier A fused kernels
// Node-per-group: group g (8 lanes) owns node ibase+g; lane's uint4 covers
// channels l8*8..l8*8+7. Gather loop runs wave-max-degree iterations with
// masked (idx->0, weight 0) edges. Matvec: W amortized over 8 nodes with
// named accumulators; row/self reads are uniform-address LDS broadcasts.

__global__ __launch_bounds__(512) void fused_gin_h_kernel(
    const __half* __restrict__ hh, const int* __restrict__ off,
    const int* __restrict__ bucket, const float* __restrict__ W,
    const float* __restrict__ eps, __half* __restrict__ outh, int n)
{
    __shared__ __half WhS[4096];          // [k4][row][e] fp16
    __shared__ __half rowh[WPB][8][64];   // 8 nodes' agg rows per wave
    int tid = threadIdx.x;
    for (int idx = tid; idx < 4096; idx += 512) {
        int row = idx >> 6, col = idx & 63;
        WhS[(col >> 3) * 512 + row * 8 + (col & 7)] = __float2half(W[idx]);
    }
    __syncthreads();
    float s = 1.0f + eps[0];
    __half2 s2 = __float2half2_rn(s);
    const __half2 one2 = __float2half2_rn(1.0f);
    const __half2 zero2 = __float2half2_rn(0.0f);
    int lane = tid & 63;
    int w = tid >> 6;
    int l8 = lane & 7;
    int g = lane >> 3;
    const uint4* Wh4 = (const uint4*)WhS;
    int octetStride = gridDim.x * WPB * 8;
    for (int ibase = (blockIdx.x * WPB + w) * 8; ibase < n; ibase += octetStride) {
        int i = ibase + g;
        bool nv = (i < n);
        int iSafe = nv ? i : 0;
        int2 be = *(const int2*)&off[iSafe];
        int j = be.x;
        int end = nv ? be.y : be.x;   // invalid node -> 0 edges
        int md = end - j;
#pragma unroll
        for (int mask = 1; mask < 64; mask <<= 1)
            md = max(md, __shfl_xor(md, mask, 64));
        __half2 aA0 = zero2, aA1 = zero2, aA2 = zero2, aA3 = zero2;
        __half2 aB0 = zero2, aB1 = zero2, aB2 = zero2, aB3 = zero2;
        for (int it = 0; it < md; it += 4) {
            int e0 = bucket[j + 0];
            int e1 = bucket[j + 1];
            int e2 = bucket[j + 2];
            int e3 = bucket[j + 3];
            bool v0 = (j + 0) < end, v1 = (j + 1) < end;
            bool v2 = (j + 2) < end, v3 = (j + 3) < end;
            int x0 = v0 ? e0 : 0, x1 = v1 ? e1 : 0;
            int x2 = v2 ? e2 : 0, x3 = v3 ? e3 : 0;
            uint4 r0 = *(const uint4*)&hh[(size_t)x0 * 64 + l8 * 8];
            uint4 r1 = *(const uint4*)&hh[(size_t)x1 * 64 + l8 * 8];
            uint4 r2 = *(const uint4*)&hh[(size_t)x2 * 64 + l8 * 8];
            uint4 r3 = *(const uint4*)&hh[(size_t)x3 * 64 + l8 * 8];
            __half2 m0 = v0 ? one2 : zero2;
            __half2 m1 = v1 ? one2 : zero2;
            __half2 m2 = v2 ? one2 : zero2;
            __half2 m3 = v3 ? one2 : zero2;
            aA0 = __hfma2(bc_h2(r0.x), m0, aA0);
            aA1 = __hfma2(bc_h2(r0.y), m0, aA1);
            aA2 = __hfma2(bc_h2(r0.z), m0, aA2);
            aA3 = __hfma2(bc_h2(r0.w), m0, aA3);
            aB0 = __hfma2(bc_h2(r1.x), m1, aB0);
            aB1 = __hfma2(bc_h2(r1.y), m1, aB1);
            aB2 = __hfma2(bc_h2(r1.z), m1, aB2);
            aB3 = __hfma2(bc_h2(r1.w), m1, aB3);
            aA0 = __hfma2(bc_h2(r2.x), m2, aA0);
            aA1 = __hfma2(bc_h2(r2.y), m2, aA1);
            aA2 = __hfma2(bc_h2(r2.z), m2, aA2);
            aA3 = __hfma2(bc_h2(r2.w), m2, aA3);
            aB0 = __hfma2(bc_h2(r3.x), m3, aB0);
            aB1 = __hfma2(bc_h2(r3.y), m3, aB1);
            aB2 = __hfma2(bc_h2(r3.z), m3, aB2);
            aB3 = __hfma2(bc_h2(r3.w), m3, aB3);
            j += 4;
        }
        aA0 = __hadd2(aA0, aB0);
        aA1 = __hadd2(aA1, aB1);
        aA2 = __hadd2(aA2, aB2);
        aA3 = __hadd2(aA3, aB3);
        {   // self term: (1+eps)*h[i]
            uint4 sv = *(const uint4*)&hh[(size_t)iSafe * 64 + l8 * 8];
            __half2 ss = nv ? s2 : zero2;
            aA0 = __hfma2(bc_h2(sv.x), ss, aA0);
            aA1 = __hfma2(bc_h2(sv.y), ss, aA1);
            aA2 = __hfma2(bc_h2(sv.z), ss, aA2);
            aA3 = __hfma2(bc_h2(sv.w), ss, aA3);
        }
        uint4 st;
        st.x = bc_u(aA0); st.y = bc_u(aA1); st.z = bc_u(aA2); st.w = bc_u(aA3);
        *(uint4*)&rowh[w][g][l8 * 8] = st;
        __builtin_amdgcn_wave_barrier();
        float o0 = 0.f, o1 = 0.f, o2 = 0.f, o3 = 0.f;
        float o4 = 0.f, o5 = 0.f, o6 = 0.f, o7 = 0.f;
#pragma unroll
        for (int k4 = 0; k4 < 8; ++k4) {
            uint4 wv = Wh4[k4 * 64 + lane];
            uint4 rv;
#define MV1(T, O) \
            rv = *(const uint4*)&rowh[w][T][k4 * 8]; \
            O = fdot2(wv.x, rv.x, O); O = fdot2(wv.y, rv.y, O); \
            O = fdot2(wv.z, rv.z, O); O = fdot2(wv.w, rv.w, O);
            MV1(0, o0) MV1(1, o1) MV1(2, o2) MV1(3, o3)
            MV1(4, o4) MV1(5, o5) MV1(6, o6) MV1(7, o7)
#undef MV1
        }
#define ST1(T, O) if (ibase + (T) < n) \
            outh[(size_t)(ibase + (T)) * 64 + lane] = __float2half(fmaxf(O, 0.f));
        ST1(0, o0) ST1(1, o1) ST1(2, o2) ST1(3, o3)
        ST1(4, o4) ST1(5, o5) ST1(6, o6) ST1(7, o7)
#undef ST1
        __builtin_amdgcn_wave_barrier();
    }
}

__global__ __launch_bounds__(512) void fused_final_h_kernel(
    const __half* __restrict__ hh1, const int* __restrict__ off,
    const int* __restrict__ bucket, const float* __restrict__ W1,
    const float* __restrict__ Wm, const float* __restrict__ eps,
    float* __restrict__ out, int n)
{
    __shared__ __half W1hS[4096];
    __shared__ __half WmhS[4096];
    __shared__ __half rowh[WPB][8][64];
    __shared__ __half selfh[WPB][8][64];
    int tid = threadIdx.x;
    for (int idx = tid; idx < 4096; idx += 512) {
        int row = idx >> 6, col = idx & 63;
        int li = (col >> 3) * 512 + row * 8 + (col & 7);
        W1hS[li] = __float2half(W1[idx]);
        WmhS[li] = __float2half(Wm[idx]);
    }
    __syncthreads();
    float s = 1.0f + eps[0];
    __half2 s2 = __float2half2_rn(s);
    const __half2 one2 = __float2half2_rn(1.0f);
    const __half2 zero2 = __float2half2_rn(0.0f);
    int lane = tid & 63;
    int w = tid >> 6;
    int l8 = lane & 7;
    int g = lane >> 3;
    const uint4* W1h4 = (const uint4*)W1hS;
    const uint4* Wmh4 = (const uint4*)WmhS;
    int octetStride = gridDim.x * WPB * 8;
    for (int ibase = (blockIdx.x * WPB + w) * 8; ibase < n; ibase += octetStride) {
        int i = ibase + g;
        bool nv = (i < n);
        int iSafe = nv ? i : 0;
        int2 be = *(const int2*)&off[iSafe];
        int j = be.x;
        int end = nv ? be.y : be.x;
        int md = end - j;
#pragma unroll
        for (int mask = 1; mask < 64; mask <<= 1)
            md = max(md, __shfl_xor(md, mask, 64));
        __half2 aA0 = zero2, aA1 = zero2, aA2 = zero2, aA3 = zero2;
        __half2 aB0 = zero2, aB1 = zero2, aB2 = zero2, aB3 = zero2;
        for (int it = 0; it < md; it += 4) {
            int e0 = bucket[j + 0];
            int e1 = bucket[j + 1];
            int e2 = bucket[j + 2];
            int e3 = bucket[j + 3];
            bool v0 = (j + 0) < end, v1 = (j + 1) < end;
            bool v2 = (j + 2) < end, v3 = (j + 3) < end;
            int x0 = v0 ? e0 : 0, x1 = v1 ? e1 : 0;
            int x2 = v2 ? e2 : 0, x3 = v3 ? e3 : 0;
            uint4 r0 = *(const uint4*)&hh1[(size_t)x0 * 64 + l8 * 8];
            uint4 r1 = *(const uint4*)&hh1[(size_t)x1 * 64 + l8 * 8];
            uint4 r2 = *(const uint4*)&hh1[(size_t)x2 * 64 + l8 * 8];
            uint4 r3 = *(const uint4*)&hh1[(size_t)x3 * 64 + l8 * 8];
            __half2 m0 = v0 ? one2 : zero2;
            __half2 m1 = v1 ? one2 : zero2;
            __half2 m2 = v2 ? one2 : zero2;
            __half2 m3 = v3 ? one2 : zero2;
            aA0 = __hfma2(bc_h2(r0.x), m0, aA0);
            aA1 = __hfma2(bc_h2(r0.y), m0, aA1);
            aA2 = __hfma2(bc_h2(r0.z), m0, aA2);
            aA3 = __hfma2(bc_h2(r0.w), m0, aA3);
            aB0 = __hfma2(bc_h2(r1.x), m1, aB0);
            aB1 = __hfma2(bc_h2(r1.y), m1, aB1);
            aB2 = __hfma2(bc_h2(r1.z), m1, aB2);
            aB3 = __hfma2(bc_h2(r1.w), m1, aB3);
            aA0 = __hfma2(bc_h2(r2.x), m2, aA0);
            aA1 = __hfma2(bc_h2(r2.y), m2, aA1);
            aA2 = __hfma2(bc_h2(r2.z), m2, aA2);
            aA3 = __hfma2(bc_h2(r2.w), m2, aA3);
            aB0 = __hfma2(bc_h2(r3.x), m3, aB0);
            aB1 = __hfma2(bc_h2(r3.y), m3, aB1);
            aB2 = __hfma2(bc_h2(r3.z), m3, aB2);
            aB3 = __hfma2(bc_h2(r3.w), m3, aB3);
            j += 4;
        }
        aA0 = __hadd2(aA0, aB0);
        aA1 = __hadd2(aA1, aB1);
        aA2 = __hadd2(aA2, aB2);
        aA3 = __hadd2(aA3, aB3);
        {
            uint4 sv = *(const uint4*)&hh1[(size_t)iSafe * 64 + l8 * 8];
            *(uint4*)&selfh[w][g][l8 * 8] = sv;
            __half2 ss = nv ? s2 : zero2;
            aA0 = __hfma2(bc_h2(sv.x), ss, aA0);
            aA1 = __hfma2(bc_h2(sv.y), ss, aA1);
            aA2 = __hfma2(bc_h2(sv.z), ss, aA2);
            aA3 = __hfma2(bc_h2(sv.w), ss, aA3);
        }
        uint4 st;
        st.x = bc_u(aA0); st.y = bc_u(aA1); st.z = bc_u(aA2); st.w = bc_u(aA3);
        *(uint4*)&rowh[w][g][l8 * 8] = st;
        __builtin_amdgcn_wave_barrier();
        float p0 = 0.f, p1 = 0.f, p2 = 0.f, p3 = 0.f;
        float p4 = 0.f, p5 = 0.f, p6 = 0.f, p7 = 0.f;
        float q0 = 0.f, q1 = 0.f, q2 = 0.f, q3 = 0.f;
        float q4 = 0.f, q5 = 0.f, q6 = 0.f, q7 = 0.f;
#pragma unroll
        for (int k4 = 0; k4 < 8; ++k4) {
            uint4 wv1 = W1h4[k4 * 64 + lane];
            uint4 wv2 = Wmh4[k4 * 64 + lane];
            uint4 rv, sv;
#define MV2(T, P, Q) \
            rv = *(const uint4*)&rowh[w][T][k4 * 8]; \
            sv = *(const uint4*)&selfh[w][T][k4 * 8]; \
            P = fdot2(wv1.x, rv.x, P); P = fdot2(wv1.y, rv.y, P); \
            P = fdot2(wv1.z, rv.z, P); P = fdot2(wv1.w, rv.w, P); \
            Q = fdot2(wv2.x, sv.x, Q); Q = fdot2(wv2.y, sv.y, Q); \
            Q = fdot2(wv2.z, sv.z, Q); Q = fdot2(wv2.w, sv.w, Q);
            MV2(0, p0, q0) MV2(1, p1, q1) MV2(2, p2, q2) MV2(3, p3, q3)
            MV2(4, p4, q4) MV2(5, p5, q5) MV2(6, p6, q6) MV2(7, p7, q7)
#undef MV2
        }
#define ST2(T, P, Q) if (ibase + (T) < n) \
            out[(size_t)(ibase + (T)) * 64 + lane] = (fmaxf(P, 0.f) + Q) * 0.5f;
        ST2(0, p0, q0) ST2(1, p1, q1) ST2(2, p2, q2) ST2(3, p3, q3)
        ST2(4, p4, q4) ST2(5, p5, q5) ST2(6, p6, q6) ST2(7, p7, q7)
#undef ST2
        __builtin_amdgcn_wave_barrier();
    }
}

// ================================================================ tier B: fp32 fused (R6-proven)
__device__ __forceinline__ float dot4(float4 a, float4 b)
{
    return a.x * b.x + a.y * b.y + a.z * b.z + a.w * b.w;
}

__device__ __forceinline__ float4 gather_row_f32(
    const float* __restrict__ h, const int* __restrict__ bucket,
    int beg, int end, int g, int l16, float4 acc4)
{
    int j = beg;
    for (; j + 8 <= end; j += 8) {
        int sa = bucket[j + g];
        int sb = bucket[j + 4 + g];
        float4 va = *(const float4*)&h[(size_t)sa * 64 + l16 * 4];
        float4 vb = *(const float4*)&h[(size_t)sb * 64 + l16 * 4];
        acc4.x += va.x + vb.x;
        acc4.y += va.y + vb.y;
        acc4.z += va.z + vb.z;
        acc4.w += va.w + vb.w;
    }
    if (j + 4 <= end) {
        int sa = bucket[j + g];
        float4 va = *(const float4*)&h[(size_t)sa * 64 + l16 * 4];
        acc4.x += va.x; acc4.y += va.y; acc4.z += va.z; acc4.w += va.w;
        j += 4;
    }
    if (j < end) {
        int jj = j + g;
        int sc = bucket[(jj < end) ? jj : (end - 1)];
        float m = (jj < end) ? 1.0f : 0.0f;
        float4 vc = *(const float4*)&h[(size_t)sc * 64 + l16 * 4];
        acc4.x = fmaf(vc.x, m, acc4.x);
        acc4.y = fmaf(vc.y, m, acc4.y);
        acc4.z = fmaf(vc.z, m, acc4.z);
        acc4.w = fmaf(vc.w, m, acc4.w);
    }
    return acc4;
}

__global__ __launch_bounds__(512) void fused_gin_kernel(
    const float* __restrict__ h, const int* __restrict__ off,
    const int* __restrict__ bucket, const float* __restrict__ W,
    const float* __restrict__ eps, float* __restrict__ out, int n)
{
    __shared__ float Ws[64][68];
    __shared__ float P[WPB][4][64];
    __shared__ float rowbuf[WPB][64];
    int tid = threadIdx.x;
    for (int idx = tid; idx < 4096; idx += 512) Ws[idx >> 6][idx & 63] = W[idx];
    __syncthreads();
    float s = 1.0f + eps[0];
    int lane = tid & 63;
    int w = tid >> 6;
    int l16 = lane & 15;
    int g = lane >> 4;
    int wavesTotal = gridDim.x * WPB;
    for (int i = blockIdx.x * WPB + w; i < n; i += wavesTotal) {
        float4 init = make_float4(0.f, 0.f, 0.f, 0.f);
        if (g == 0) {
            float4 self4 = *(const float4*)&h[(size_t)i * 64 + l16 * 4];
            init = make_float4(s * self4.x, s * self4.y, s * self4.z, s * self4.w);
        }
        int2 be = *(const int2*)&off[i];
        int beg = __builtin_amdgcn_readfirstlane(be.x);
        int end = __builtin_amdgcn_readfirstlane(be.y);
        float4 acc4 = gather_row_f32(h, bucket, beg, end, g, l16, init);
        *(float4*)&P[w][g][l16 * 4] = acc4;
        __builtin_amdgcn_wave_barrier();
        float r0 = P[w][0][lane], r1 = P[w][1][lane];
        float r2 = P[w][2][lane], r3 = P[w][3][lane];
        rowbuf[w][lane] = (r0 + r1) + (r2 + r3);
        __builtin_amdgcn_wave_barrier();
        const float4* wrow = (const float4*)&Ws[lane][0];
        const float4* rrow = (const float4*)&rowbuf[w][0];
        float o = 0.f;
#pragma unroll
        for (int k4 = 0; k4 < 16; ++k4) o += dot4(wrow[k4], rrow[k4]);
        out[(size_t)i * 64 + lane] = fmaxf(o, 0.f);
        __builtin_amdgcn_wave_barrier();
    }
}

__global__ __launch_bounds__(512) void fused_final_csr_kernel(
    const float* __restrict__ h1, const int* __restrict__ off,
    const int* __restrict__ bucket, const float* __restrict__ W1,
    const float* __restrict__ Wm, const float* __restrict__ eps,
    float* __restrict__ out, int n)
{
    __shared__ float W1s[64][68];
    __shared__ float Wms[64][68];
    __shared__ float P[WPB][4][64];
    __shared__ float rowbuf[WPB][64];
    __shared__ float selfbuf[WPB][64];
    int tid = threadIdx.x;
    for (int idx = tid; idx < 4096; idx += 512) {
        W1s[idx >> 6][idx & 63] = W1[idx];
        Wms[idx >> 6][idx & 63] = Wm[idx];
    }
    __syncthreads();
    float s = 1.0f + eps[0];
    int lane = tid & 63;
    int w = tid >> 6;
    int l16 = lane & 15;
    int g = lane >> 4;
    int wavesTotal = gridDim.x * WPB;
    for (int i = blockIdx.x * WPB + w; i < n; i += wavesTotal) {
        float4 init = make_float4(0.f, 0.f, 0.f, 0.f);
        if (g == 0) {
            float4 self4 = *(const float4*)&h1[(size_t)i * 64 + l16 * 4];
            *(float4*)&selfbuf[w][l16 * 4] = self4;
            init = make_float4(s * self4.x, s * self4.y, s * self4.z, s * self4.w);
        }
        int2 be = *(const int2*)&off[i];
        int beg = __builtin_amdgcn_readfirstlane(be.x);
        int end = __builtin_amdgcn_readfirstlane(be.y);
        float4 acc4 = gather_row_f32(h1, bucket, beg, end, g, l16, init);
        *(float4*)&P[w][g][l16 * 4] = acc4;
        __builtin_amdgcn_wave_barrier();
        float r0 = P[w][0][lane], r1 = P[w][1][lane];
        float r2 = P[w][2][lane], r3 = P[w][3][lane];
        rowbuf[w][lane] = (r0 + r1) + (r2 + r3);
        __builtin_amdgcn_wave_barrier();
        const float4* w1row = (const float4*)&W1s[lane][0];
        const float4* wmrow = (const float4*)&Wms[lane][0];
        const float4* rrow  = (const float4*)&rowbuf[w][0];
        const float4* srow  = (const float4*)&selfbuf[w][0];
        float o1 = 0.f, o2 = 0.f;
#pragma unroll
        for (int k4 = 0; k4 < 16; ++k4) {
            o1 += dot4(w1row[k4], rrow[k4]);
            o2 += dot4(wmrow[k4], srow[k4]);
        }
        out[(size_t)i * 64 + lane] = (fmaxf(o1, 0.f) + o2) * 0.5f;
        __builtin_amdgcn_wave_barrier();
    }
}

// ================================================================ tier C: atomic scatter
__global__ __launch_bounds__(256) void init_scale_kernel(
    const float* __restrict__ h, const float* __restrict__ eps,
    float* __restrict__ agg, int total4)
{
    float s = 1.0f + eps[0];
    int i = blockIdx.x * blockDim.x + threadIdx.x;
    int stride = gridDim.x * blockDim.x;
    const float4* h4 = (const float4*)h;
    float4* a4 = (float4*)agg;
    for (; i < total4; i += stride) {
        float4 v = h4[i];
        v.x *= s; v.y *= s; v.z *= s; v.w *= s;
        a4[i] = v;
    }
}

__global__ __launch_bounds__(256) void scatter_kernel(
    const float* __restrict__ h, const int* __restrict__ src,
    const int* __restrict__ dst, float* __restrict__ agg, int E)
{
    int lane = threadIdx.x & 63;
    int e = blockIdx.x * 4 + (threadIdx.x >> 6);
    if (e >= E) return;
    int s = src[e];
    int d = dst[e];
    atomicAdd(&agg[(size_t)d * 64 + lane], h[(size_t)s * 64 + lane]);
}

__global__ __launch_bounds__(256) void gemm_relu_kernel(
    const float* __restrict__ A, const float* __restrict__ W,
    float* __restrict__ out, int n)
{
    __shared__ float Wt[64][65];
    __shared__ float rowbuf[4][64];
    int tid = threadIdx.x;
    for (int i = tid; i < 4096; i += 256) Wt[i & 63][i >> 6] = W[i];
    __syncthreads();
    int lane = tid & 63;
    int w = tid >> 6;
    int wavesTotal = gridDim.x * 4;
    for (int i = blockIdx.x * 4 + w; i < n; i += wavesTotal) {
        rowbuf[w][lane] = A[(size_t)i * 64 + lane];
        __builtin_amdgcn_wave_barrier();
        float o = 0.f;
#pragma unroll
        for (int k = 0; k < 64; ++k) o += rowbuf[w][k] * Wt[k][lane];
        out[(size_t)i * 64 + lane] = fmaxf(o, 0.f);
        __builtin_amdgcn_wave_barrier();
    }
}

__global__ __launch_bounds__(256) void final_kernel(
    const float* __restrict__ Agg, const float* __restrict__ H1,
    const float* __restrict__ W1, const float* __restrict__ Wm,
    float* __restrict__ out, int n)
{
    __shared__ float W1t[64][65];
    __shared__ float Wmt[64][65];
    __shared__ float rowbuf[4][64];
    __shared__ float selfbuf[4][64];
    int tid = threadIdx.x;
    for (int i = tid; i < 4096; i += 256) {
        W1t[i & 63][i >> 6] = W1[i];
        Wmt[i & 63][i >> 6] = Wm[i];
    }
    __syncthreads();
    int lane = tid & 63;
    int w = tid >> 6;
    int wavesTotal = gridDim.x * 4;
    for (int i = blockIdx.x * 4 + w; i < n; i += wavesTotal) {
        rowbuf[w][lane] = Agg[(size_t)i * 64 + lane];
        selfbuf[w][lane] = H1[(size_t)i * 64 + lane];
        __builtin_amdgcn_wave_barrier();
        float o1 = 0.f, o2 = 0.f;
#pragma unroll
        for (int k = 0; k < 64; ++k) {
            o1 += rowbuf[w][k] * W1t[k][lane];
            o2 += selfbuf[w][k] * Wmt[k][lane];
        }
        out[(size_t)i * 64 + lane] = (fmaxf(o1, 0.f) + o2) * 0.5f;
        __builtin_amdgcn_wave_barrier();
    }
}

// ================================================================ launch
extern "C" void kernel_launch(void* const* d_in, const int* in_sizes, int n_in,
                              void* d_out, int out_size, void* d_ws, size_t ws_size,
                              hipStream_t stream)
{
    const float* x    = (const float*)d_in[0];
    const int*   ei   = (const int*)d_in[1];
    const float* W0   = (const float*)d_in[2];
    const float* eps0 = (const float*)d_in[3];
    const float* W1   = (const float*)d_in[4];
    const float* eps1 = (const float*)d_in[5];
    const float* Wm   = (const float*)d_in[6];
    float* out = (float*)d_out;

    int n = in_sizes[0] / 64;   // 100000
    int E = in_sizes[1] / 2;    // 1600000
    const int* src = ei;
    const int* dst = ei + E;

    auto align1k = [](size_t v) { return (v + 1023) & ~(size_t)1023; };

    // ---- tier A layout (fp16 mirrors; bucket has +64 slack for masked reads)
    size_t hhx_off    = 0;
    size_t hh1_off    = align1k(hhx_off + (size_t)n * 64 * 2);
    size_t off_off    = align1k(hh1_off + (size_t)n * 64 * 2);
    size_t deg_off    = align1k(off_off + (size_t)(n + 1) * 4);
    size_t bsum_off   = align1k(deg_off + (size_t)n * 4);
    size_t bucket_off = align1k(bsum_off + 256 * 4);
    size_t rank_off   = align1k(bucket_off + (size_t)(E + 64) * 4);
    size_t need_A2    = rank_off + (size_t)E * 4;

    // ---- tier B layout (fp32, cursor fill; ~33.2 MB)
    size_t b_h1_off     = 0;
    size_t b_off_off    = align1k(b_h1_off + (size_t)n * 64 * 4);
    size_t b_deg_off    = align1k(b_off_off + (size_t)(n + 1) * 4);
    size_t b_cursor_off = align1k(b_deg_off + (size_t)n * 4);
    size_t b_bsum_off   = align1k(b_cursor_off + (size_t)n * 4);
    size_t b_bucket_off = align1k(b_bsum_off + 256 * 4);
    size_t need_B       = b_bucket_off + (size_t)E * 4;

    int nb = (n + 1023) / 1024;            // <=256 required
    int e8Blocks  = (E + 2047) / 2048;
    int e16Blocks = (E + 4095) / 4096;
    int total4 = n * 16;
    int fusedBlocks = 784;  // 6272 waves x 8 nodes: ~all waves do exactly 2 octets

    if (ws_size >= need_A2) {
        __half* hhx  = (__half*)((char*)d_ws + hhx_off);
        __half* hh1  = (__half*)((char*)d_ws + hh1_off);
        int* off     = (int*)((char*)d_ws + off_off);
        int* deg     = (int*)((char*)d_ws + deg_off);
        int* bsum    = (int*)((char*)d_ws + bsum_off);
        int* bucket  = (int*)((char*)d_ws + bucket_off);
        int* rank    = (int*)((char*)d_ws + rank_off);

        zero_int_kernel<<<256, 256, 0, stream>>>(deg, n);
        f32_to_f16_kernel<<<2048, 256, 0, stream>>>(x, hhx, total4);
        hist_rank_kernel<<<e16Blocks, 256, 0, stream>>>(dst, deg, rank, E);
        scanA_kernel<<<nb, 256, 0, stream>>>(deg, off, bsum, n);
        scanB_kernel<<<1, 256, 0, stream>>>(bsum, nb);
        scanC_kernel<<<nb, 256, 0, stream>>>(off, (int*)nullptr, bsum, n, E);
        fill_rank_kernel<<<e8Blocks, 256, 0, stream>>>(src, dst, rank, off, bucket, E);

        // gin: 16KB LDS; final: 32KB LDS -> both 4 blocks/CU capable
        fused_gin_h_kernel<<<fusedBlocks, 512, 0, stream>>>(hhx, off, bucket, W0, eps0, hh1, n);
        fused_final_h_kernel<<<fusedBlocks, 512, 0, stream>>>(hh1, off, bucket, W1, Wm, eps1, out, n);
    } else if (ws_size >= need_B) {
        float* h1    = (float*)((char*)d_ws + b_h1_off);
        int* off     = (int*)((char*)d_ws + b_off_off);
        int* deg     = (int*)((char*)d_ws + b_deg_off);
        int* cursor  = (int*)((char*)d_ws + b_cursor_off);
        int* bsum    = (int*)((char*)d_ws + b_bsum_off);
        int* bucket  = (int*)((char*)d_ws + b_bucket_off);

        zero_int_kernel<<<256, 256, 0, stream>>>(deg, n);
        hist_kernel<<<(E + 1023) / 1024, 256, 0, stream>>>(dst, deg, E);
        scanA_kernel<<<nb, 256, 0, stream>>>(deg, off, bsum, n);
        scanB_kernel<<<1, 256, 0, stream>>>(bsum, nb);
        scanC_kernel<<<nb, 256, 0, stream>>>(off, cursor, bsum, n, E);
        fill_kernel<<<(E + 255) / 256, 256, 0, stream>>>(src, dst, cursor, bucket, E);

        fused_gin_kernel<<<1024, 512, 0, stream>>>(x, off, bucket, W0, eps0, h1, n);
        fused_final_csr_kernel<<<768, 512, 0, stream>>>(h1, off, bucket, W1, Wm, eps1, out, n);
    } else {
        float* agg = (float*)d_ws;
        float* h1  = out;
        int scatterBlocks = (E + 3) / 4;

        init_scale_kernel<<<2048, 256, 0, stream>>>(x, eps0, agg, total4);
        scatter_kernel<<<scatterBlocks, 256, 0, stream>>>(x, src, dst, agg, E);
        gemm_relu_kernel<<<2048, 256, 0, stream>>>(agg, W0, h1, n);
        init_scale_kernel<<<2048, 256, 0, stream>>>(h1, eps1, agg, total4);
        scatter_kernel<<<scatterBlocks, 256, 0, stream>>>(h1, src, dst, agg, E);
        final_kernel<<<2048, 256, 0, stream>>>(agg, h1, W1, Wm, out, n);
    }
}

// Round 12
// 309.866 us; speedup vs baseline: 1.8157x; 1.8157x over previous
//
#include <hip/hip_runtime.h>
#include <hip/hip_fp16.h>

// GIN: h1 = relu((scatter_add(x) + (1+eps0)*x) @ W0^T)
//      h2 = relu((scatter_add(h1) + (1+eps1)*h1) @ W1^T)
//      out = (h1 @ Wm^T + h2) / 2
//
// R12: node-per-group, slimmed. R11's mechanism (8 independent gather chains
// per wave = 8x MLP at constant per-lane register cost) was right; its
// implementation spilled (VGPR 128, WRITE 882MB). R12 keeps the mechanism:
//  - divergent group-local edge loop (exec mask reconverges; no wave-max
//    shuffle, no mask ALU, no clamped loads), 2 edges/iter, dual accum sets
//  - matvec split into 4+4 nodes (<=8 live fp32 accums in final)
//  - ONE octet (8 nodes) per wave; grid ceil(n/64)=1563 -> HW scheduler
//    load-balances ~6 blocks/CU
// CSR build (rank-hist + atomic-free fill) and tiers B/C unchanged (R10).

// ================================================================ CSR build
__global__ __launch_bounds__(256) void zero_int_kernel(int* __restrict__ p, int n)
{
    int i = blockIdx.x * blockDim.x + threadIdx.x;
    int stride = gridDim.x * blockDim.x;
    for (; i < n; i += stride) p[i] = 0;
}

__global__ __launch_bounds__(256) void hist_rank_kernel(
    const int* __restrict__ dst, int* __restrict__ deg,
    int* __restrict__ rank, int E)
{
    int base = (blockIdx.x * blockDim.x + threadIdx.x) * 16;
    if (base + 15 < E) {
        int4 a = *(const int4*)&dst[base];
        int4 b = *(const int4*)&dst[base + 4];
        int4 c = *(const int4*)&dst[base + 8];
        int4 d = *(const int4*)&dst[base + 12];
        int r0 = atomicAdd(&deg[a.x], 1);
        int r1 = atomicAdd(&deg[a.y], 1);
        int r2 = atomicAdd(&deg[a.z], 1);
        int r3 = atomicAdd(&deg[a.w], 1);
        int r4 = atomicAdd(&deg[b.x], 1);
        int r5 = atomicAdd(&deg[b.y], 1);
        int r6 = atomicAdd(&deg[b.z], 1);
        int r7 = atomicAdd(&deg[b.w], 1);
        int r8 = atomicAdd(&deg[c.x], 1);
        int r9 = atomicAdd(&deg[c.y], 1);
        int rA = atomicAdd(&deg[c.z], 1);
        int rB = atomicAdd(&deg[c.w], 1);
        int rC = atomicAdd(&deg[d.x], 1);
        int rD = atomicAdd(&deg[d.y], 1);
        int rE = atomicAdd(&deg[d.z], 1);
        int rF = atomicAdd(&deg[d.w], 1);
        *(int4*)&rank[base]      = make_int4(r0, r1, r2, r3);
        *(int4*)&rank[base + 4]  = make_int4(r4, r5, r6, r7);
        *(int4*)&rank[base + 8]  = make_int4(r8, r9, rA, rB);
        *(int4*)&rank[base + 12] = make_int4(rC, rD, rE, rF);
    } else {
        for (int e = base; e < E; ++e) rank[e] = atomicAdd(&deg[dst[e]], 1);
    }
}

__global__ __launch_bounds__(256) void hist_kernel(
    const int* __restrict__ dst, int* __restrict__ deg, int E)
{
    int e4 = (blockIdx.x * blockDim.x + threadIdx.x) * 4;
    if (e4 + 3 < E) {
        int4 d = *(const int4*)&dst[e4];
        atomicAdd(&deg[d.x], 1);
        atomicAdd(&deg[d.y], 1);
        atomicAdd(&deg[d.z], 1);
        atomicAdd(&deg[d.w], 1);
    } else {
        for (int e = e4; e < E; ++e) atomicAdd(&deg[dst[e]], 1);
    }
}

__global__ __launch_bounds__(256) void scanA_kernel(
    const int* __restrict__ deg, int* __restrict__ off,
    int* __restrict__ bsum, int n)
{
    __shared__ int tmp[256];
    int t = threadIdx.x;
    int base = blockIdx.x * 1024 + t * 4;
    int v0 = 0, v1 = 0, v2 = 0, v3 = 0;
    if (base + 3 < n) {
        int4 q = *(const int4*)&deg[base];
        v0 = q.x; v1 = q.y; v2 = q.z; v3 = q.w;
    } else {
        if (base + 0 < n) v0 = deg[base + 0];
        if (base + 1 < n) v1 = deg[base + 1];
        if (base + 2 < n) v2 = deg[base + 2];
    }
    int tot = v0 + v1 + v2 + v3;
    tmp[t] = tot;
    __syncthreads();
    for (int d = 1; d < 256; d <<= 1) {
        int x = (t >= d) ? tmp[t - d] : 0;
        __syncthreads();
        tmp[t] += x;
        __syncthreads();
    }
    int incl = tmp[t];
    int p = incl - tot;
    if (base + 0 < n) off[base + 0] = p;
    if (base + 1 < n) off[base + 1] = p + v0;
    if (base + 2 < n) off[base + 2] = p + v0 + v1;
    if (base + 3 < n) off[base + 3] = p + v0 + v1 + v2;
    if (t == 255) bsum[blockIdx.x] = incl;
}

__global__ __launch_bounds__(256) void scanB_kernel(int* __restrict__ bsum, int nb)
{
    __shared__ int tmp[256];
    int t = threadIdx.x;
    int v = (t < nb) ? bsum[t] : 0;
    tmp[t] = v;
    __syncthreads();
    for (int d = 1; d < 256; d <<= 1) {
        int x = (t >= d) ? tmp[t - d] : 0;
        __syncthreads();
        tmp[t] += x;
        __syncthreads();
    }
    if (t < nb) bsum[t] = tmp[t] - v;
}

__global__ __launch_bounds__(256) void scanC_kernel(
    int* __restrict__ off, int* __restrict__ cursor,
    const int* __restrict__ bsum, int n, int E)
{
    int t = threadIdx.x;
    int add = bsum[blockIdx.x];
    int base = blockIdx.x * 1024 + t * 4;
#pragma unroll
    for (int q = 0; q < 4; ++q) {
        int idx = base + q;
        if (idx < n) {
            int v = off[idx] + add;
            off[idx] = v;
            if (cursor) cursor[idx] = v;
        }
    }
    if (blockIdx.x == 0 && t == 0) off[n] = E;
}

__global__ __launch_bounds__(256) void fill_rank_kernel(
    const int* __restrict__ src, const int* __restrict__ dst,
    const int* __restrict__ rank, const int* __restrict__ off,
    int* __restrict__ bucket, int E)
{
    int base = (blockIdx.x * blockDim.x + threadIdx.x) * 8;
    if (base + 7 < E) {
        int4 d0 = *(const int4*)&dst[base];
        int4 d1 = *(const int4*)&dst[base + 4];
        int4 r0 = *(const int4*)&rank[base];
        int4 r1 = *(const int4*)&rank[base + 4];
        int4 s0 = *(const int4*)&src[base];
        int4 s1 = *(const int4*)&src[base + 4];
        bucket[off[d0.x] + r0.x] = s0.x;
        bucket[off[d0.y] + r0.y] = s0.y;
        bucket[off[d0.z] + r0.z] = s0.z;
        bucket[off[d0.w] + r0.w] = s0.w;
        bucket[off[d1.x] + r1.x] = s1.x;
        bucket[off[d1.y] + r1.y] = s1.y;
        bucket[off[d1.z] + r1.z] = s1.z;
        bucket[off[d1.w] + r1.w] = s1.w;
    } else {
        for (int e = base; e < E; ++e) bucket[off[dst[e]] + rank[e]] = src[e];
    }
}

__global__ __launch_bounds__(256) void fill_kernel(
    const int* __restrict__ src, const int* __restrict__ dst,
    int* __restrict__ cursor, int* __restrict__ bucket, int E)
{
    int e = blockIdx.x * blockDim.x + threadIdx.x;
    if (e < E) {
        int d = dst[e];
        int p = atomicAdd(&cursor[d], 1);
        bucket[p] = src[e];
    }
}

// ================================================================ fp32 -> fp16 convert
__global__ __launch_bounds__(256) void f32_to_f16_kernel(
    const float* __restrict__ in, __half* __restrict__ out, int total4)
{
    int i = blockIdx.x * blockDim.x + threadIdx.x;
    int stride = gridDim.x * blockDim.x;
    const float4* in4 = (const float4*)in;
    uint2* out4 = (uint2*)out;
    for (; i < total4; i += stride) {
        float4 v = in4[i];
        __half2 a = __floats2half2_rn(v.x, v.y);
        __half2 b = __floats2half2_rn(v.z, v.w);
        uint2 u;
        u.x = __builtin_bit_cast(unsigned int, a);
        u.y = __builtin_bit_cast(unsigned int, b);
        out4[i] = u;
    }
}

// ================================================================ helpers
#define WPB 8  // waves per 512-thread block

__device__ __forceinline__ __half2 bc_h2(unsigned int u)
{
    return __builtin_bit_cast(__half2, u);
}
__device__ __forceinline__ unsigned int bc_u(__half2 h)
{
    return __builtin_bit_cast(unsigned int, h);
}

#if __has_builtin(__builtin_amdgcn_fdot2)
typedef _Float16 half2_v __attribute__((ext_vector_type(2)));
__device__ __forceinline__ float fdot2(unsigned int a, unsigned int b, float c)
{
    return __builtin_amdgcn_fdot2(__builtin_bit_cast(half2_v, a),
                                  __builtin_bit_cast(half2_v, b), c, false);
}
#else
__device__ __forceinline__ float fdot2(unsigned int a, unsigned int b, float c)
{
    float2 af = __half22float2(bc_h2(a));
    float2 bf = __half22float2(bc_h2(b));
    return fmaf(af.x, bf.x, fmaf(af.y, bf.y, c));
}
#endif

// ================================================================ tier A fused kernels
// Node-per-group: group g (8 lanes) owns node ibase+g; lane's uint4 covers
// channels l8*8..l8*8+7. Group loops its OWN degree (divergent loop, exec
// mask reconverges) with 2 edges/iter into dual accumulator sets.
// W LDS: flat fp16, idx(k4,row,e) = k4*512 + row*8 + e, read as uint4.

__global__ __launch_bounds__(512) void fused_gin_h_kernel(
    const __half* __restrict__ hh, const int* __restrict__ off,
    const int* __restrict__ bucket, const float* __restrict__ W,
    const float* __restrict__ eps, __half* __restrict__ outh, int n)
{
    __shared__ __half WhS[4096];          // [k4][row][e]
    __shared__ __half rowh[WPB][8][64];   // 8 nodes' agg rows per wave
    int tid = threadIdx.x;
    for (int idx = tid; idx < 4096; idx += 512) {
        int row = idx >> 6, col = idx & 63;
        WhS[(col >> 3) * 512 + row * 8 + (col & 7)] = __float2half(W[idx]);
    }
    __syncthreads();
    float s = 1.0f + eps[0];
    __half2 s2 = __float2half2_rn(s);
    const __half2 zero2 = __float2half2_rn(0.0f);
    int lane = tid & 63;
    int w = tid >> 6;
    int l8 = lane & 7;
    int g = lane >> 3;
    const uint4* Wh4 = (const uint4*)WhS;
    int ibase = (blockIdx.x * WPB + w) * 8;   // one octet per wave
    if (ibase >= n) return;
    {
        int i = ibase + g;
        bool nv = (i < n);
        int iSafe = nv ? i : 0;
        int2 be = *(const int2*)&off[iSafe];
        int j = be.x;
        int end = nv ? be.y : be.x;
        __half2 aA0 = zero2, aA1 = zero2, aA2 = zero2, aA3 = zero2;
        __half2 aB0 = zero2, aB1 = zero2, aB2 = zero2, aB3 = zero2;
        while (j + 2 <= end) {            // group-local divergent loop
            int e0 = bucket[j];
            int e1 = bucket[j + 1];
            uint4 r0 = *(const uint4*)&hh[(size_t)e0 * 64 + l8 * 8];
            uint4 r1 = *(const uint4*)&hh[(size_t)e1 * 64 + l8 * 8];
            aA0 = __hadd2(aA0, bc_h2(r0.x));
            aA1 = __hadd2(aA1, bc_h2(r0.y));
            aA2 = __hadd2(aA2, bc_h2(r0.z));
            aA3 = __hadd2(aA3, bc_h2(r0.w));
            aB0 = __hadd2(aB0, bc_h2(r1.x));
            aB1 = __hadd2(aB1, bc_h2(r1.y));
            aB2 = __hadd2(aB2, bc_h2(r1.z));
            aB3 = __hadd2(aB3, bc_h2(r1.w));
            j += 2;
        }
        if (j < end) {
            int e0 = bucket[j];
            uint4 r0 = *(const uint4*)&hh[(size_t)e0 * 64 + l8 * 8];
            aA0 = __hadd2(aA0, bc_h2(r0.x));
            aA1 = __hadd2(aA1, bc_h2(r0.y));
            aA2 = __hadd2(aA2, bc_h2(r0.z));
            aA3 = __hadd2(aA3, bc_h2(r0.w));
        }
        aA0 = __hadd2(aA0, aB0);
        aA1 = __hadd2(aA1, aB1);
        aA2 = __hadd2(aA2, aB2);
        aA3 = __hadd2(aA3, aB3);
        {   // self term (1+eps)*h[i]
            uint4 sv = *(const uint4*)&hh[(size_t)iSafe * 64 + l8 * 8];
            __half2 ss = nv ? s2 : zero2;
            aA0 = __hfma2(bc_h2(sv.x), ss, aA0);
            aA1 = __hfma2(bc_h2(sv.y), ss, aA1);
            aA2 = __hfma2(bc_h2(sv.z), ss, aA2);
            aA3 = __hfma2(bc_h2(sv.w), ss, aA3);
        }
        uint4 st;
        st.x = bc_u(aA0); st.y = bc_u(aA1); st.z = bc_u(aA2); st.w = bc_u(aA3);
        *(uint4*)&rowh[w][g][l8 * 8] = st;
    }
    __builtin_amdgcn_wave_barrier();
    float o0 = 0.f, o1 = 0.f, o2 = 0.f, o3 = 0.f;
    float o4 = 0.f, o5 = 0.f, o6 = 0.f, o7 = 0.f;
#pragma unroll
    for (int k4 = 0; k4 < 8; ++k4) {
        uint4 wv = Wh4[k4 * 64 + lane];
        uint4 rv;
#define MV1(T, O) \
        rv = *(const uint4*)&rowh[w][T][k4 * 8]; \
        O = fdot2(wv.x, rv.x, O); O = fdot2(wv.y, rv.y, O); \
        O = fdot2(wv.z, rv.z, O); O = fdot2(wv.w, rv.w, O);
        MV1(0, o0) MV1(1, o1) MV1(2, o2) MV1(3, o3)
        MV1(4, o4) MV1(5, o5) MV1(6, o6) MV1(7, o7)
#undef MV1
    }
#define ST1(T, O) if (ibase + (T) < n) \
        outh[(size_t)(ibase + (T)) * 64 + lane] = __float2half(fmaxf(O, 0.f));
    ST1(0, o0) ST1(1, o1) ST1(2, o2) ST1(3, o3)
    ST1(4, o4) ST1(5, o5) ST1(6, o6) ST1(7, o7)
#undef ST1
}

__global__ __launch_bounds__(512) void fused_final_h_kernel(
    const __half* __restrict__ hh1, const int* __restrict__ off,
    const int* __restrict__ bucket, const float* __restrict__ W1,
    const float* __restrict__ Wm, const float* __restrict__ eps,
    float* __restrict__ out, int n)
{
    __shared__ __half W1hS[4096];
    __shared__ __half WmhS[4096];
    __shared__ __half rowh[WPB][8][64];
    __shared__ __half selfh[WPB][8][64];
    int tid = threadIdx.x;
    for (int idx = tid; idx < 4096; idx += 512) {
        int row = idx >> 6, col = idx & 63;
        int li = (col >> 3) * 512 + row * 8 + (col & 7);
        W1hS[li] = __float2half(W1[idx]);
        WmhS[li] = __float2half(Wm[idx]);
    }
    __syncthreads();
    float s = 1.0f + eps[0];
    __half2 s2 = __float2half2_rn(s);
    const __half2 zero2 = __float2half2_rn(0.0f);
    int lane = tid & 63;
    int w = tid >> 6;
    int l8 = lane & 7;
    int g = lane >> 3;
    const uint4* W1h4 = (const uint4*)W1hS;
    const uint4* Wmh4 = (const uint4*)WmhS;
    int ibase = (blockIdx.x * WPB + w) * 8;
    if (ibase >= n) return;
    {
        int i = ibase + g;
        bool nv = (i < n);
        int iSafe = nv ? i : 0;
        int2 be = *(const int2*)&off[iSafe];
        int j = be.x;
        int end = nv ? be.y : be.x;
        __half2 aA0 = zero2, aA1 = zero2, aA2 = zero2, aA3 = zero2;
        __half2 aB0 = zero2, aB1 = zero2, aB2 = zero2, aB3 = zero2;
        while (j + 2 <= end) {
            int e0 = bucket[j];
            int e1 = bucket[j + 1];
            uint4 r0 = *(const uint4*)&hh1[(size_t)e0 * 64 + l8 * 8];
            uint4 r1 = *(const uint4*)&hh1[(size_t)e1 * 64 + l8 * 8];
            aA0 = __hadd2(aA0, bc_h2(r0.x));
            aA1 = __hadd2(aA1, bc_h2(r0.y));
            aA2 = __hadd2(aA2, bc_h2(r0.z));
            aA3 = __hadd2(aA3, bc_h2(r0.w));
            aB0 = __hadd2(aB0, bc_h2(r1.x));
            aB1 = __hadd2(aB1, bc_h2(r1.y));
            aB2 = __hadd2(aB2, bc_h2(r1.z));
            aB3 = __hadd2(aB3, bc_h2(r1.w));
            j += 2;
        }
        if (j < end) {
            int e0 = bucket[j];
            uint4 r0 = *(const uint4*)&hh1[(size_t)e0 * 64 + l8 * 8];
            aA0 = __hadd2(aA0, bc_h2(r0.x));
            aA1 = __hadd2(aA1, bc_h2(r0.y));
            aA2 = __hadd2(aA2, bc_h2(r0.z));
            aA3 = __hadd2(aA3, bc_h2(r0.w));
        }
        aA0 = __hadd2(aA0, aB0);
        aA1 = __hadd2(aA1, aB1);
        aA2 = __hadd2(aA2, aB2);
        aA3 = __hadd2(aA3, aB3);
        {   // stash self + add (1+eps)*self
            uint4 sv = *(const uint4*)&hh1[(size_t)iSafe * 64 + l8 * 8];
            *(uint4*)&selfh[w][g][l8 * 8] = sv;
            __half2 ss = nv ? s2 : zero2;
            aA0 = __hfma2(bc_h2(sv.x), ss, aA0);
            aA1 = __hfma2(bc_h2(sv.y), ss, aA1);
            aA2 = __hfma2(bc_h2(sv.z), ss, aA2);
            aA3 = __hfma2(bc_h2(sv.w), ss, aA3);
        }
        uint4 st;
        st.x = bc_u(aA0); st.y = bc_u(aA1); st.z = bc_u(aA2); st.w = bc_u(aA3);
        *(uint4*)&rowh[w][g][l8 * 8] = st;
    }
    __builtin_amdgcn_wave_barrier();
    // matvec in two batches of 4 nodes to bound live accumulators
#define MVBATCH(T0, T1, T2, T3)                                            \
    {                                                                      \
        float p0 = 0.f, p1 = 0.f, p2 = 0.f, p3 = 0.f;                      \
        float q0 = 0.f, q1 = 0.f, q2 = 0.f, q3 = 0.f;                      \
        _Pragma("unroll")                                                  \
        for (int k4 = 0; k4 < 8; ++k4) {                                   \
            uint4 wv1 = W1h4[k4 * 64 + lane];                              \
            uint4 wv2 = Wmh4[k4 * 64 + lane];                              \
            uint4 rv, sv;                                                  \
            rv = *(const uint4*)&rowh[w][T0][k4 * 8];                      \
            sv = *(const uint4*)&selfh[w][T0][k4 * 8];                     \
            p0 = fdot2(wv1.x, rv.x, p0); p0 = fdot2(wv1.y, rv.y, p0);      \
            p0 = fdot2(wv1.z, rv.z, p0); p0 = fdot2(wv1.w, rv.w, p0);      \
            q0 = fdot2(wv2.x, sv.x, q0); q0 = fdot2(wv2.y, sv.y, q0);      \
            q0 = fdot2(wv2.z, sv.z, q0); q0 = fdot2(wv2.w, sv.w, q0);      \
            rv = *(const uint4*)&rowh[w][T1][k4 * 8];                      \
            sv = *(const uint4*)&selfh[w][T1][k4 * 8];                     \
            p1 = fdot2(wv1.x, rv.x, p1); p1 = fdot2(wv1.y, rv.y, p1);      \
            p1 = fdot2(wv1.z, rv.z, p1); p1 = fdot2(wv1.w, rv.w, p1);      \
            q1 = fdot2(wv2.x, sv.x, q1); q1 = fdot2(wv2.y, sv.y, q1);      \
            q1 = fdot2(wv2.z, sv.z, q1); q1 = fdot2(wv2.w, sv.w, q1);      \
            rv = *(const uint4*)&rowh[w][T2][k4 * 8];                      \
            sv = *(const uint4*)&selfh[w][T2][k4 * 8];                     \
            p2 = fdot2(wv1.x, rv.x, p2); p2 = fdot2(wv1.y, rv.y, p2);      \
            p2 = fdot2(wv1.z, rv.z, p2); p2 = fdot2(wv1.w, rv.w, p2);      \
            q2 = fdot2(wv2.x, sv.x, q2); q2 = fdot2(wv2.y, sv.y, q2);      \
            q2 = fdot2(wv2.z, sv.z, q2); q2 = fdot2(wv2.w, sv.w, q2);      \
            rv = *(const uint4*)&rowh[w][T3][k4 * 8];                      \
            sv = *(const uint4*)&selfh[w][T3][k4 * 8];                     \
            p3 = fdot2(wv1.x, rv.x, p3); p3 = fdot2(wv1.y, rv.y, p3);      \
            p3 = fdot2(wv1.z, rv.z, p3); p3 = fdot2(wv1.w, rv.w, p3);      \
            q3 = fdot2(wv2.x, sv.x, q3); q3 = fdot2(wv2.y, sv.y, q3);      \
            q3 = fdot2(wv2.z, sv.z, q3); q3 = fdot2(wv2.w, sv.w, q3);      \
        }                                                                  \
        if (ibase + (T0) < n)                                              \
            out[(size_t)(ibase + (T0)) * 64 + lane] = (fmaxf(p0, 0.f) + q0) * 0.5f; \
        if (ibase + (T1) < n)                                              \
            out[(size_t)(ibase + (T1)) * 64 + lane] = (fmaxf(p1, 0.f) + q1) * 0.5f; \
        if (ibase + (T2) < n)                                              \
            out[(size_t)(ibase + (T2)) * 64 + lane] = (fmaxf(p2, 0.f) + q2) * 0.5f; \
        if (ibase + (T3) < n)                                              \
            out[(size_t)(ibase + (T3)) * 64 + lane] = (fmaxf(p3, 0.f) + q3) * 0.5f; \
    }
    MVBATCH(0, 1, 2, 3)
    MVBATCH(4, 5, 6, 7)
#undef MVBATCH
}

// ================================================================ tier B: fp32 fused (R6-proven)
__device__ __forceinline__ float dot4(float4 a, float4 b)
{
    return a.x * b.x + a.y * b.y + a.z * b.z + a.w * b.w;
}

__device__ __forceinline__ float4 gather_row_f32(
    const float* __restrict__ h, const int* __restrict__ bucket,
    int beg, int end, int g, int l16, float4 acc4)
{
    int j = beg;
    for (; j + 8 <= end; j += 8) {
        int sa = bucket[j + g];
        int sb = bucket[j + 4 + g];
        float4 va = *(const float4*)&h[(size_t)sa * 64 + l16 * 4];
        float4 vb = *(const float4*)&h[(size_t)sb * 64 + l16 * 4];
        acc4.x += va.x + vb.x;
        acc4.y += va.y + vb.y;
        acc4.z += va.z + vb.z;
        acc4.w += va.w + vb.w;
    }
    if (j + 4 <= end) {
        int sa = bucket[j + g];
        float4 va = *(const float4*)&h[(size_t)sa * 64 + l16 * 4];
        acc4.x += va.x; acc4.y += va.y; acc4.z += va.z; acc4.w += va.w;
        j += 4;
    }
    if (j < end) {
        int jj = j + g;
        int sc = bucket[(jj < end) ? jj : (end - 1)];
        float m = (jj < end) ? 1.0f : 0.0f;
        float4 vc = *(const float4*)&h[(size_t)sc * 64 + l16 * 4];
        acc4.x = fmaf(vc.x, m, acc4.x);
        acc4.y = fmaf(vc.y, m, acc4.y);
        acc4.z = fmaf(vc.z, m, acc4.z);
        acc4.w = fmaf(vc.w, m, acc4.w);
    }
    return acc4;
}

__global__ __launch_bounds__(512) void fused_gin_kernel(
    const float* __restrict__ h, const int* __restrict__ off,
    const int* __restrict__ bucket, const float* __restrict__ W,
    const float* __restrict__ eps, float* __restrict__ out, int n)
{
    __shared__ float Ws[64][68];
    __shared__ float P[WPB][4][64];
    __shared__ float rowbuf[WPB][64];
    int tid = threadIdx.x;
    for (int idx = tid; idx < 4096; idx += 512) Ws[idx >> 6][idx & 63] = W[idx];
    __syncthreads();
    float s = 1.0f + eps[0];
    int lane = tid & 63;
    int w = tid >> 6;
    int l16 = lane & 15;
    int g = lane >> 4;
    int wavesTotal = gridDim.x * WPB;
    for (int i = blockIdx.x * WPB + w; i < n; i += wavesTotal) {
        float4 init = make_float4(0.f, 0.f, 0.f, 0.f);
        if (g == 0) {
            float4 self4 = *(const float4*)&h[(size_t)i * 64 + l16 * 4];
            init = make_float4(s * self4.x, s * self4.y, s * self4.z, s * self4.w);
        }
        int2 be = *(const int2*)&off[i];
        int beg = __builtin_amdgcn_readfirstlane(be.x);
        int end = __builtin_amdgcn_readfirstlane(be.y);
        float4 acc4 = gather_row_f32(h, bucket, beg, end, g, l16, init);
        *(float4*)&P[w][g][l16 * 4] = acc4;
        __builtin_amdgcn_wave_barrier();
        float r0 = P[w][0][lane], r1 = P[w][1][lane];
        float r2 = P[w][2][lane], r3 = P[w][3][lane];
        rowbuf[w][lane] = (r0 + r1) + (r2 + r3);
        __builtin_amdgcn_wave_barrier();
        const float4* wrow = (const float4*)&Ws[lane][0];
        const float4* rrow = (const float4*)&rowbuf[w][0];
        float o = 0.f;
#pragma unroll
        for (int k4 = 0; k4 < 16; ++k4) o += dot4(wrow[k4], rrow[k4]);
        out[(size_t)i * 64 + lane] = fmaxf(o, 0.f);
        __builtin_amdgcn_wave_barrier();
    }
}

__global__ __launch_bounds__(512) void fused_final_csr_kernel(
    const float* __restrict__ h1, const int* __restrict__ off,
    const int* __restrict__ bucket, const float* __restrict__ W1,
    const float* __restrict__ Wm, const float* __restrict__ eps,
    float* __restrict__ out, int n)
{
    __shared__ float W1s[64][68];
    __shared__ float Wms[64][68];
    __shared__ float P[WPB][4][64];
    __shared__ float rowbuf[WPB][64];
    __shared__ float selfbuf[WPB][64];
    int tid = threadIdx.x;
    for (int idx = tid; idx < 4096; idx += 512) {
        W1s[idx >> 6][idx & 63] = W1[idx];
        Wms[idx >> 6][idx & 63] = Wm[idx];
    }
    __syncthreads();
    float s = 1.0f + eps[0];
    int lane = tid & 63;
    int w = tid >> 6;
    int l16 = lane & 15;
    int g = lane >> 4;
    int wavesTotal = gridDim.x * WPB;
    for (int i = blockIdx.x * WPB + w; i < n; i += wavesTotal) {
        float4 init = make_float4(0.f, 0.f, 0.f, 0.f);
        if (g == 0) {
            float4 self4 = *(const float4*)&h1[(size_t)i * 64 + l16 * 4];
            *(float4*)&selfbuf[w][l16 * 4] = self4;
            init = make_float4(s * self4.x, s * self4.y, s * self4.z, s * self4.w);
        }
        int2 be = *(const int2*)&off[i];
        int beg = __builtin_amdgcn_readfirstlane(be.x);
        int end = __builtin_amdgcn_readfirstlane(be.y);
        float4 acc4 = gather_row_f32(h1, bucket, beg, end, g, l16, init);
        *(float4*)&P[w][g][l16 * 4] = acc4;
        __builtin_amdgcn_wave_barrier();
        float r0 = P[w][0][lane], r1 = P[w][1][lane];
        float r2 = P[w][2][lane], r3 = P[w][3][lane];
        rowbuf[w][lane] = (r0 + r1) + (r2 + r3);
        __builtin_amdgcn_wave_barrier();
        const float4* w1row = (const float4*)&W1s[lane][0];
        const float4* wmrow = (const float4*)&Wms[lane][0];
        const float4* rrow  = (const float4*)&rowbuf[w][0];
        const float4* srow  = (const float4*)&selfbuf[w][0];
        float o1 = 0.f, o2 = 0.f;
#pragma unroll
        for (int k4 = 0; k4 < 16; ++k4) {
            o1 += dot4(w1row[k4], rrow[k4]);
            o2 += dot4(wmrow[k4], srow[k4]);
        }
        out[(size_t)i * 64 + lane] = (fmaxf(o1, 0.f) + o2) * 0.5f;
        __builtin_amdgcn_wave_barrier();
    }
}

// ================================================================ tier C: atomic scatter
__global__ __launch_bounds__(256) void init_scale_kernel(
    const float* __restrict__ h, const float* __restrict__ eps,
    float* __restrict__ agg, int total4)
{
    float s = 1.0f + eps[0];
    int i = blockIdx.x * blockDim.x + threadIdx.x;
    int stride = gridDim.x * blockDim.x;
    const float4* h4 = (const float4*)h;
    float4* a4 = (float4*)agg;
    for (; i < total4; i += stride) {
        float4 v = h4[i];
        v.x *= s; v.y *= s; v.z *= s; v.w *= s;
        a4[i] = v;
    }
}

__global__ __launch_bounds__(256) void scatter_kernel(
    const float* __restrict__ h, const int* __restrict__ src,
    const int* __restrict__ dst, float* __restrict__ agg, int E)
{
    int lane = threadIdx.x & 63;
    int e = blockIdx.x * 4 + (threadIdx.x >> 6);
    if (e >= E) return;
    int s = src[e];
    int d = dst[e];
    atomicAdd(&agg[(size_t)d * 64 + lane], h[(size_t)s * 64 + lane]);
}

__global__ __launch_bounds__(256) void gemm_relu_kernel(
    const float* __restrict__ A, const float* __restrict__ W,
    float* __restrict__ out, int n)
{
    __shared__ float Wt[64][65];
    __shared__ float rowbuf[4][64];
    int tid = threadIdx.x;
    for (int i = tid; i < 4096; i += 256) Wt[i & 63][i >> 6] = W[i];
    __syncthreads();
    int lane = tid & 63;
    int w = tid >> 6;
    int wavesTotal = gridDim.x * 4;
    for (int i = blockIdx.x * 4 + w; i < n; i += wavesTotal) {
        rowbuf[w][lane] = A[(size_t)i * 64 + lane];
        __builtin_amdgcn_wave_barrier();
        float o = 0.f;
#pragma unroll
        for (int k = 0; k < 64; ++k) o += rowbuf[w][k] * Wt[k][lane];
        out[(size_t)i * 64 + lane] = fmaxf(o, 0.f);
        __builtin_amdgcn_wave_barrier();
    }
}

__global__ __launch_bounds__(256) void final_kernel(
    const float* __restrict__ Agg, const float* __restrict__ H1,
    const float* __restrict__ W1, const float* __restrict__ Wm,
    float* __restrict__ out, int n)
{
    __shared__ float W1t[64][65];
    __shared__ float Wmt[64][65];
    __shared__ float rowbuf[4][64];
    __shared__ float selfbuf[4][64];
    int tid = threadIdx.x;
    for (int i = tid; i < 4096; i += 256) {
        W1t[i & 63][i >> 6] = W1[i];
        Wmt[i & 63][i >> 6] = Wm[i];
    }
    __syncthreads();
    int lane = tid & 63;
    int w = tid >> 6;
    int wavesTotal = gridDim.x * 4;
    for (int i = blockIdx.x * 4 + w; i < n; i += wavesTotal) {
        rowbuf[w][lane] = Agg[(size_t)i * 64 + lane];
        selfbuf[w][lane] = H1[(size_t)i * 64 + lane];
        __builtin_amdgcn_wave_barrier();
        float o1 = 0.f, o2 = 0.f;
#pragma unroll
        for (int k = 0; k < 64; ++k) {
            o1 += rowbuf[w][k] * W1t[k][lane];
            o2 += selfbuf[w][k] * Wmt[k][lane];
        }
        out[(size_t)i * 64 + lane] = (fmaxf(o1, 0.f) + o2) * 0.5f;
        __builtin_amdgcn_wave_barrier();
    }
}

// ================================================================ launch
extern "C" void kernel_launch(void* const* d_in, const int* in_sizes, int n_in,
                              void* d_out, int out_size, void* d_ws, size_t ws_size,
                              hipStream_t stream)
{
    const float* x    = (const float*)d_in[0];
    const int*   ei   = (const int*)d_in[1];
    const float* W0   = (const float*)d_in[2];
    const float* eps0 = (const float*)d_in[3];
    const float* W1   = (const float*)d_in[4];
    const float* eps1 = (const float*)d_in[5];
    const float* Wm   = (const float*)d_in[6];
    float* out = (float*)d_out;

    int n = in_sizes[0] / 64;   // 100000
    int E = in_sizes[1] / 2;    // 1600000
    const int* src = ei;
    const int* dst = ei + E;

    auto align1k = [](size_t v) { return (v + 1023) & ~(size_t)1023; };

    // ---- tier A layout (fp16 mirrors; ~39.3 MB)
    size_t hhx_off    = 0;
    size_t hh1_off    = align1k(hhx_off + (size_t)n * 64 * 2);
    size_t off_off    = align1k(hh1_off + (size_t)n * 64 * 2);
    size_t deg_off    = align1k(off_off + (size_t)(n + 1) * 4);
    size_t bsum_off   = align1k(deg_off + (size_t)n * 4);
    size_t bucket_off = align1k(bsum_off + 256 * 4);
    size_t rank_off   = align1k(bucket_off + (size_t)(E + 64) * 4);
    size_t need_A2    = rank_off + (size_t)E * 4;

    // ---- tier B layout (fp32, cursor fill; ~33.2 MB)
    size_t b_h1_off     = 0;
    size_t b_off_off    = align1k(b_h1_off + (size_t)n * 64 * 4);
    size_t b_deg_off    = align1k(b_off_off + (size_t)(n + 1) * 4);
    size_t b_cursor_off = align1k(b_deg_off + (size_t)n * 4);
    size_t b_bsum_off   = align1k(b_cursor_off + (size_t)n * 4);
    size_t b_bucket_off = align1k(b_bsum_off + 256 * 4);
    size_t need_B       = b_bucket_off + (size_t)E * 4;

    int nb = (n + 1023) / 1024;            // <=256 required
    int e8Blocks  = (E + 2047) / 2048;
    int e16Blocks = (E + 4095) / 4096;
    int total4 = n * 16;
    int fusedBlocks = (n + 63) / 64;       // one octet (8 nodes) per wave

    if (ws_size >= need_A2) {
        __half* hhx  = (__half*)((char*)d_ws + hhx_off);
        __half* hh1  = (__half*)((char*)d_ws + hh1_off);
        int* off     = (int*)((char*)d_ws + off_off);
        int* deg     = (int*)((char*)d_ws + deg_off);
        int* bsum    = (int*)((char*)d_ws + bsum_off);
        int* bucket  = (int*)((char*)d_ws + bucket_off);
        int* rank    = (int*)((char*)d_ws + rank_off);

        zero_int_kernel<<<256, 256, 0, stream>>>(deg, n);
        f32_to_f16_kernel<<<2048, 256, 0, stream>>>(x, hhx, total4);
        hist_rank_kernel<<<e16Blocks, 256, 0, stream>>>(dst, deg, rank, E);
        scanA_kernel<<<nb, 256, 0, stream>>>(deg, off, bsum, n);
        scanB_kernel<<<1, 256, 0, stream>>>(bsum, nb);
        scanC_kernel<<<nb, 256, 0, stream>>>(off, (int*)nullptr, bsum, n, E);
        fill_rank_kernel<<<e8Blocks, 256, 0, stream>>>(src, dst, rank, off, bucket, E);

        // gin 16KB LDS, final 32KB LDS; ~6 blocks/CU queued, HW-balanced
        fused_gin_h_kernel<<<fusedBlocks, 512, 0, stream>>>(hhx, off, bucket, W0, eps0, hh1, n);
        fused_final_h_kernel<<<fusedBlocks, 512, 0, stream>>>(hh1, off, bucket, W1, Wm, eps1, out, n);
    } else if (ws_size >= need_B) {
        float* h1    = (float*)((char*)d_ws + b_h1_off);
        int* off     = (int*)((char*)d_ws + b_off_off);
        int* deg     = (int*)((char*)d_ws + b_deg_off);
        int* cursor  = (int*)((char*)d_ws + b_cursor_off);
        int* bsum    = (int*)((char*)d_ws + b_bsum_off);
        int* bucket  = (int*)((char*)d_ws + b_bucket_off);

        zero_int_kernel<<<256, 256, 0, stream>>>(deg, n);
        hist_kernel<<<(E + 1023) / 1024, 256, 0, stream>>>(dst, deg, E);
        scanA_kernel<<<nb, 256, 0, stream>>>(deg, off, bsum, n);
        scanB_kernel<<<1, 256, 0, stream>>>(bsum, nb);
        scanC_kernel<<<nb, 256, 0, stream>>>(off, cursor, bsum, n, E);
        fill_kernel<<<(E + 255) / 256, 256, 0, stream>>>(src, dst, cursor, bucket, E);

        fused_gin_kernel<<<1024, 512, 0, stream>>>(x, off, bucket, W0, eps0, h1, n);
        fused_final_csr_kernel<<<768, 512, 0, stream>>>(h1, off, bucket, W1, Wm, eps1, out, n);
    } else {
        float* agg = (float*)d_ws;
        float* h1  = out;
        int scatterBlocks = (E + 3) / 4;

        init_scale_kernel<<<2048, 256, 0, stream>>>(x, eps0, agg, total4);
        scatter_kernel<<<scatterBlocks, 256, 0, stream>>>(x, src, dst, agg, E);
        gemm_relu_kernel<<<2048, 256, 0, stream>>>(agg, W0, h1, n);
        init_scale_kernel<<<2048, 256, 0, stream>>>(h1, eps1, agg, total4);
        scatter_kernel<<<scatterBlocks, 256, 0, stream>>>(h1, src, dst, agg, E);
        final_kernel<<<2048, 256, 0, stream>>>(agg, h1, W1, Wm, out, n);
    }
}

// Round 13
// 219.765 us; speedup vs baseline: 2.5601x; 1.4100x over previous
//
#include <hip/hip_runtime.h>
#include <hip/hip_fp16.h>

// GIN: h1 = relu((scatter_add(x) + (1+eps0)*x) @ W0^T)
//      h2 = relu((scatter_add(h1) + (1+eps1)*h1) @ W1^T)
//      out = (h1 @ Wm^T + h2) / 2
//
// R13: revert tier A to the PROVEN R10 kernels (225us; node-per-group
// variants R11/R12 spill intrinsically -> abandoned). Two safe changes:
//  - fused grids 1024->2048: R10 ran exactly 4 blocks/CU (the 32-wave cap)
//    with NO replacement pool -> degree-variance tail (occ 41%). 2048 gives
//    each CU a queue of ~8 blocks, halves nodes/wave, HW rebalances.
//  - zero_int + f32->f16 convert fused into one prelude kernel (one less
//    launch).
// CSR build (rank-hist + atomic-free fill) and tiers B/C unchanged.

// ================================================================ CSR build
__global__ __launch_bounds__(256) void zero_convert_kernel(
    int* __restrict__ deg, int n,
    const float* __restrict__ in, __half* __restrict__ outh, int total4)
{
    int i = blockIdx.x * blockDim.x + threadIdx.x;
    int stride = gridDim.x * blockDim.x;
    for (int k = i; k < n; k += stride) deg[k] = 0;
    const float4* in4 = (const float4*)in;
    uint2* out4 = (uint2*)outh;
    for (int k = i; k < total4; k += stride) {
        float4 v = in4[k];
        __half2 a = __floats2half2_rn(v.x, v.y);
        __half2 b = __floats2half2_rn(v.z, v.w);
        uint2 u;
        u.x = __builtin_bit_cast(unsigned int, a);
        u.y = __builtin_bit_cast(unsigned int, b);
        out4[k] = u;
    }
}

__global__ __launch_bounds__(256) void zero_int_kernel(int* __restrict__ p, int n)
{
    int i = blockIdx.x * blockDim.x + threadIdx.x;
    int stride = gridDim.x * blockDim.x;
    for (; i < n; i += stride) p[i] = 0;
}

__global__ __launch_bounds__(256) void hist_rank_kernel(
    const int* __restrict__ dst, int* __restrict__ deg,
    int* __restrict__ rank, int E)
{
    int base = (blockIdx.x * blockDim.x + threadIdx.x) * 16;
    if (base + 15 < E) {
        int4 a = *(const int4*)&dst[base];
        int4 b = *(const int4*)&dst[base + 4];
        int4 c = *(const int4*)&dst[base + 8];
        int4 d = *(const int4*)&dst[base + 12];
        int r0 = atomicAdd(&deg[a.x], 1);
        int r1 = atomicAdd(&deg[a.y], 1);
        int r2 = atomicAdd(&deg[a.z], 1);
        int r3 = atomicAdd(&deg[a.w], 1);
        int r4 = atomicAdd(&deg[b.x], 1);
        int r5 = atomicAdd(&deg[b.y], 1);
        int r6 = atomicAdd(&deg[b.z], 1);
        int r7 = atomicAdd(&deg[b.w], 1);
        int r8 = atomicAdd(&deg[c.x], 1);
        int r9 = atomicAdd(&deg[c.y], 1);
        int rA = atomicAdd(&deg[c.z], 1);
        int rB = atomicAdd(&deg[c.w], 1);
        int rC = atomicAdd(&deg[d.x], 1);
        int rD = atomicAdd(&deg[d.y], 1);
        int rE = atomicAdd(&deg[d.z], 1);
        int rF = atomicAdd(&deg[d.w], 1);
        *(int4*)&rank[base]      = make_int4(r0, r1, r2, r3);
        *(int4*)&rank[base + 4]  = make_int4(r4, r5, r6, r7);
        *(int4*)&rank[base + 8]  = make_int4(r8, r9, rA, rB);
        *(int4*)&rank[base + 12] = make_int4(rC, rD, rE, rF);
    } else {
        for (int e = base; e < E; ++e) rank[e] = atomicAdd(&deg[dst[e]], 1);
    }
}

__global__ __launch_bounds__(256) void hist_kernel(
    const int* __restrict__ dst, int* __restrict__ deg, int E)
{
    int e4 = (blockIdx.x * blockDim.x + threadIdx.x) * 4;
    if (e4 + 3 < E) {
        int4 d = *(const int4*)&dst[e4];
        atomicAdd(&deg[d.x], 1);
        atomicAdd(&deg[d.y], 1);
        atomicAdd(&deg[d.z], 1);
        atomicAdd(&deg[d.w], 1);
    } else {
        for (int e = e4; e < E; ++e) atomicAdd(&deg[dst[e]], 1);
    }
}

__global__ __launch_bounds__(256) void scanA_kernel(
    const int* __restrict__ deg, int* __restrict__ off,
    int* __restrict__ bsum, int n)
{
    __shared__ int tmp[256];
    int t = threadIdx.x;
    int base = blockIdx.x * 1024 + t * 4;
    int v0 = 0, v1 = 0, v2 = 0, v3 = 0;
    if (base + 3 < n) {
        int4 q = *(const int4*)&deg[base];
        v0 = q.x; v1 = q.y; v2 = q.z; v3 = q.w;
    } else {
        if (base + 0 < n) v0 = deg[base + 0];
        if (base + 1 < n) v1 = deg[base + 1];
        if (base + 2 < n) v2 = deg[base + 2];
    }
    int tot = v0 + v1 + v2 + v3;
    tmp[t] = tot;
    __syncthreads();
    for (int d = 1; d < 256; d <<= 1) {
        int x = (t >= d) ? tmp[t - d] : 0;
        __syncthreads();
        tmp[t] += x;
        __syncthreads();
    }
    int incl = tmp[t];
    int p = incl - tot;
    if (base + 0 < n) off[base + 0] = p;
    if (base + 1 < n) off[base + 1] = p + v0;
    if (base + 2 < n) off[base + 2] = p + v0 + v1;
    if (base + 3 < n) off[base + 3] = p + v0 + v1 + v2;
    if (t == 255) bsum[blockIdx.x] = incl;
}

__global__ __launch_bounds__(256) void scanB_kernel(int* __restrict__ bsum, int nb)
{
    __shared__ int tmp[256];
    int t = threadIdx.x;
    int v = (t < nb) ? bsum[t] : 0;
    tmp[t] = v;
    __syncthreads();
    for (int d = 1; d < 256; d <<= 1) {
        int x = (t >= d) ? tmp[t - d] : 0;
        __syncthreads();
        tmp[t] += x;
        __syncthreads();
    }
    if (t < nb) bsum[t] = tmp[t] - v;
}

__global__ __launch_bounds__(256) void scanC_kernel(
    int* __restrict__ off, int* __restrict__ cursor,
    const int* __restrict__ bsum, int n, int E)
{
    int t = threadIdx.x;
    int add = bsum[blockIdx.x];
    int base = blockIdx.x * 1024 + t * 4;
#pragma unroll
    for (int q = 0; q < 4; ++q) {
        int idx = base + q;
        if (idx < n) {
            int v = off[idx] + add;
            off[idx] = v;
            if (cursor) cursor[idx] = v;
        }
    }
    if (blockIdx.x == 0 && t == 0) off[n] = E;
}

__global__ __launch_bounds__(256) void fill_rank_kernel(
    const int* __restrict__ src, const int* __restrict__ dst,
    const int* __restrict__ rank, const int* __restrict__ off,
    int* __restrict__ bucket, int E)
{
    int base = (blockIdx.x * blockDim.x + threadIdx.x) * 8;
    if (base + 7 < E) {
        int4 d0 = *(const int4*)&dst[base];
        int4 d1 = *(const int4*)&dst[base + 4];
        int4 r0 = *(const int4*)&rank[base];
        int4 r1 = *(const int4*)&rank[base + 4];
        int4 s0 = *(const int4*)&src[base];
        int4 s1 = *(const int4*)&src[base + 4];
        bucket[off[d0.x] + r0.x] = s0.x;
        bucket[off[d0.y] + r0.y] = s0.y;
        bucket[off[d0.z] + r0.z] = s0.z;
        bucket[off[d0.w] + r0.w] = s0.w;
        bucket[off[d1.x] + r1.x] = s1.x;
        bucket[off[d1.y] + r1.y] = s1.y;
        bucket[off[d1.z] + r1.z] = s1.z;
        bucket[off[d1.w] + r1.w] = s1.w;
    } else {
        for (int e = base; e < E; ++e) bucket[off[dst[e]] + rank[e]] = src[e];
    }
}

__global__ __launch_bounds__(256) void fill_kernel(
    const int* __restrict__ src, const int* __restrict__ dst,
    int* __restrict__ cursor, int* __restrict__ bucket, int E)
{
    int e = blockIdx.x * blockDim.x + threadIdx.x;
    if (e < E) {
        int d = dst[e];
        int p = atomicAdd(&cursor[d], 1);
        bucket[p] = src[e];
    }
}

// ================================================================ helpers
#define WPB 8  // waves per 512-thread block

__device__ __forceinline__ __half2 bc_h2(unsigned int u)
{
    return __builtin_bit_cast(__half2, u);
}
__device__ __forceinline__ unsigned int bc_u(__half2 h)
{
    return __builtin_bit_cast(unsigned int, h);
}

#if __has_builtin(__builtin_amdgcn_fdot2)
typedef _Float16 half2_v __attribute__((ext_vector_type(2)));
__device__ __forceinline__ float fdot2(unsigned int a, unsigned int b, float c)
{
    return __builtin_amdgcn_fdot2(__builtin_bit_cast(half2_v, a),
                                  __builtin_bit_cast(half2_v, b), c, false);
}
#else
__device__ __forceinline__ float fdot2(unsigned int a, unsigned int b, float c)
{
    float2 af = __half22float2(bc_h2(a));
    float2 bf = __half22float2(bc_h2(b));
    return fmaf(af.x, bf.x, fmaf(af.y, bf.y, c));
}
#endif

// ================================================================ tier A fused kernels (R10-proven)
// Gather: one node per wave, 8 groups x 8 lanes x uint4 (8 edges/VMEM instr);
// cross-group reduce via shfl_xor(8/16/32) on packed fp16. Matvec: fp16 W in
// [k4][row][e] flat LDS (uint4 reads, conflict-free) via fdot2.

// cross-group (8 groups of 8 lanes) packed-fp16 reduce of 4 half2 words
__device__ __forceinline__ void xreduce4(__half2& a0, __half2& a1,
                                         __half2& a2, __half2& a3)
{
#pragma unroll
    for (int mask = 8; mask <= 32; mask <<= 1) {
        a0 = __hadd2(a0, bc_h2((unsigned int)__shfl_xor((int)bc_u(a0), mask, 64)));
        a1 = __hadd2(a1, bc_h2((unsigned int)__shfl_xor((int)bc_u(a1), mask, 64)));
        a2 = __hadd2(a2, bc_h2((unsigned int)__shfl_xor((int)bc_u(a2), mask, 64)));
        a3 = __hadd2(a3, bc_h2((unsigned int)__shfl_xor((int)bc_u(a3), mask, 64)));
    }
}

// gather one node's row: 8 groups x 8 lanes, uint4 (8 fp16) per lane.
__device__ __forceinline__ void gather8(
    const __half* __restrict__ hh, const int* __restrict__ bucket,
    int beg, int end, int g, int l8,
    __half2& a0, __half2& a1, __half2& a2, __half2& a3)
{
    int j = beg;
    for (; j + 16 <= end; j += 16) {
        int sa = bucket[j + g];
        int sb = bucket[j + 8 + g];
        uint4 va = *(const uint4*)&hh[(size_t)sa * 64 + l8 * 8];
        uint4 vb = *(const uint4*)&hh[(size_t)sb * 64 + l8 * 8];
        a0 = __hadd2(__hadd2(a0, bc_h2(va.x)), bc_h2(vb.x));
        a1 = __hadd2(__hadd2(a1, bc_h2(va.y)), bc_h2(vb.y));
        a2 = __hadd2(__hadd2(a2, bc_h2(va.z)), bc_h2(vb.z));
        a3 = __hadd2(__hadd2(a3, bc_h2(va.w)), bc_h2(vb.w));
    }
    if (j + 8 <= end) {
        int sa = bucket[j + g];
        uint4 va = *(const uint4*)&hh[(size_t)sa * 64 + l8 * 8];
        a0 = __hadd2(a0, bc_h2(va.x));
        a1 = __hadd2(a1, bc_h2(va.y));
        a2 = __hadd2(a2, bc_h2(va.z));
        a3 = __hadd2(a3, bc_h2(va.w));
        j += 8;
    }
    if (j < end) {  // 1..7 tail edges, masked
        int jj = j + g;
        int sc = bucket[(jj < end) ? jj : (end - 1)];
        __half2 m2 = __float2half2_rn((jj < end) ? 1.0f : 0.0f);
        uint4 vc = *(const uint4*)&hh[(size_t)sc * 64 + l8 * 8];
        a0 = __hfma2(bc_h2(vc.x), m2, a0);
        a1 = __hfma2(bc_h2(vc.y), m2, a1);
        a2 = __hfma2(bc_h2(vc.z), m2, a2);
        a3 = __hfma2(bc_h2(vc.w), m2, a3);
    }
}

__global__ __launch_bounds__(512) void fused_gin_h_kernel(
    const __half* __restrict__ hh, const int* __restrict__ off,
    const int* __restrict__ bucket, const float* __restrict__ W,
    const float* __restrict__ eps, __half* __restrict__ outh, int n)
{
    __shared__ __half WhS[4096];       // [k4][row][e] fp16
    __shared__ __half rowh[WPB][64];
    int tid = threadIdx.x;
    for (int idx = tid; idx < 4096; idx += 512) {
        int row = idx >> 6, col = idx & 63;
        WhS[(col >> 3) * 512 + row * 8 + (col & 7)] = __float2half(W[idx]);
    }
    __syncthreads();
    float s = 1.0f + eps[0];
    __half2 s2 = __float2half2_rn(s);
    int lane = tid & 63;
    int w = tid >> 6;
    int l8 = lane & 7;
    int g = lane >> 3;
    int wavesTotal = gridDim.x * WPB;
    const uint4* Wh4 = (const uint4*)WhS;
    for (int i = blockIdx.x * WPB + w; i < n; i += wavesTotal) {
        int2 be = *(const int2*)&off[i];
        int beg = __builtin_amdgcn_readfirstlane(be.x);
        int end = __builtin_amdgcn_readfirstlane(be.y);
        __half2 a0 = bc_h2(0u), a1 = bc_h2(0u), a2 = bc_h2(0u), a3 = bc_h2(0u);
        gather8(hh, bucket, beg, end, g, l8, a0, a1, a2, a3);
        xreduce4(a0, a1, a2, a3);
        if (g == 0) {  // add (1+eps)*self, store row (lanes 0..7 cover 64ch)
            uint4 sv = *(const uint4*)&hh[(size_t)i * 64 + l8 * 8];
            a0 = __hfma2(bc_h2(sv.x), s2, a0);
            a1 = __hfma2(bc_h2(sv.y), s2, a1);
            a2 = __hfma2(bc_h2(sv.z), s2, a2);
            a3 = __hfma2(bc_h2(sv.w), s2, a3);
            uint4 st;
            st.x = bc_u(a0); st.y = bc_u(a1); st.z = bc_u(a2); st.w = bc_u(a3);
            *(uint4*)&rowh[w][l8 * 8] = st;
        }
        __builtin_amdgcn_wave_barrier();
        float o = 0.f;
#pragma unroll
        for (int k4 = 0; k4 < 8; ++k4) {
            uint4 wv = Wh4[k4 * 64 + lane];
            uint4 rv = *(const uint4*)&rowh[w][k4 * 8];
            o = fdot2(wv.x, rv.x, o);
            o = fdot2(wv.y, rv.y, o);
            o = fdot2(wv.z, rv.z, o);
            o = fdot2(wv.w, rv.w, o);
        }
        outh[(size_t)i * 64 + lane] = __float2half(fmaxf(o, 0.f));
        __builtin_amdgcn_wave_barrier();
    }
}

__global__ __launch_bounds__(512) void fused_final_h_kernel(
    const __half* __restrict__ hh1, const int* __restrict__ off,
    const int* __restrict__ bucket, const float* __restrict__ W1,
    const float* __restrict__ Wm, const float* __restrict__ eps,
    float* __restrict__ out, int n)
{
    __shared__ __half W1hS[4096];
    __shared__ __half WmhS[4096];
    __shared__ __half rowh[WPB][64];
    __shared__ __half selfh[WPB][64];
    int tid = threadIdx.x;
    for (int idx = tid; idx < 4096; idx += 512) {
        int row = idx >> 6, col = idx & 63;
        int li = (col >> 3) * 512 + row * 8 + (col & 7);
        W1hS[li] = __float2half(W1[idx]);
        WmhS[li] = __float2half(Wm[idx]);
    }
    __syncthreads();
    float s = 1.0f + eps[0];
    __half2 s2 = __float2half2_rn(s);
    int lane = tid & 63;
    int w = tid >> 6;
    int l8 = lane & 7;
    int g = lane >> 3;
    int wavesTotal = gridDim.x * WPB;
    const uint4* W1h4 = (const uint4*)W1hS;
    const uint4* Wmh4 = (const uint4*)WmhS;
    for (int i = blockIdx.x * WPB + w; i < n; i += wavesTotal) {
        int2 be = *(const int2*)&off[i];
        int beg = __builtin_amdgcn_readfirstlane(be.x);
        int end = __builtin_amdgcn_readfirstlane(be.y);
        __half2 a0 = bc_h2(0u), a1 = bc_h2(0u), a2 = bc_h2(0u), a3 = bc_h2(0u);
        gather8(hh1, bucket, beg, end, g, l8, a0, a1, a2, a3);
        xreduce4(a0, a1, a2, a3);
        if (g == 0) {  // stash self, add (1+eps)*self, store row
            uint4 sv = *(const uint4*)&hh1[(size_t)i * 64 + l8 * 8];
            *(uint4*)&selfh[w][l8 * 8] = sv;
            a0 = __hfma2(bc_h2(sv.x), s2, a0);
            a1 = __hfma2(bc_h2(sv.y), s2, a1);
            a2 = __hfma2(bc_h2(sv.z), s2, a2);
            a3 = __hfma2(bc_h2(sv.w), s2, a3);
            uint4 st;
            st.x = bc_u(a0); st.y = bc_u(a1); st.z = bc_u(a2); st.w = bc_u(a3);
            *(uint4*)&rowh[w][l8 * 8] = st;
        }
        __builtin_amdgcn_wave_barrier();
        float o1 = 0.f, o2 = 0.f;
#pragma unroll
        for (int k4 = 0; k4 < 8; ++k4) {
            uint4 wv1 = W1h4[k4 * 64 + lane];
            uint4 wv2 = Wmh4[k4 * 64 + lane];
            uint4 rv  = *(const uint4*)&rowh[w][k4 * 8];
            uint4 sv  = *(const uint4*)&selfh[w][k4 * 8];
            o1 = fdot2(wv1.x, rv.x, o1);
            o1 = fdot2(wv1.y, rv.y, o1);
            o1 = fdot2(wv1.z, rv.z, o1);
            o1 = fdot2(wv1.w, rv.w, o1);
            o2 = fdot2(wv2.x, sv.x, o2);
            o2 = fdot2(wv2.y, sv.y, o2);
            o2 = fdot2(wv2.z, sv.z, o2);
            o2 = fdot2(wv2.w, sv.w, o2);
        }
        out[(size_t)i * 64 + lane] = (fmaxf(o1, 0.f) + o2) * 0.5f;
        __builtin_amdgcn_wave_barrier();
    }
}

// ================================================================ tier B: fp32 fused (R6-proven)
__device__ __forceinline__ float dot4(float4 a, float4 b)
{
    return a.x * b.x + a.y * b.y + a.z * b.z + a.w * b.w;
}

__device__ __forceinline__ float4 gather_row_f32(
    const float* __restrict__ h, const int* __restrict__ bucket,
    int beg, int end, int g, int l16, float4 acc4)
{
    int j = beg;
    for (; j + 8 <= end; j += 8) {
        int sa = bucket[j + g];
        int sb = bucket[j + 4 + g];
        float4 va = *(const float4*)&h[(size_t)sa * 64 + l16 * 4];
        float4 vb = *(const float4*)&h[(size_t)sb * 64 + l16 * 4];
        acc4.x += va.x + vb.x;
        acc4.y += va.y + vb.y;
        acc4.z += va.z + vb.z;
        acc4.w += va.w + vb.w;
    }
    if (j + 4 <= end) {
        int sa = bucket[j + g];
        float4 va = *(const float4*)&h[(size_t)sa * 64 + l16 * 4];
        acc4.x += va.x; acc4.y += va.y; acc4.z += va.z; acc4.w += va.w;
        j += 4;
    }
    if (j < end) {
        int jj = j + g;
        int sc = bucket[(jj < end) ? jj : (end - 1)];
        float m = (jj < end) ? 1.0f : 0.0f;
        float4 vc = *(const float4*)&h[(size_t)sc * 64 + l16 * 4];
        acc4.x = fmaf(vc.x, m, acc4.x);
        acc4.y = fmaf(vc.y, m, acc4.y);
        acc4.z = fmaf(vc.z, m, acc4.z);
        acc4.w = fmaf(vc.w, m, acc4.w);
    }
    return acc4;
}

__global__ __launch_bounds__(512) void fused_gin_kernel(
    const float* __restrict__ h, const int* __restrict__ off,
    const int* __restrict__ bucket, const float* __restrict__ W,
    const float* __restrict__ eps, float* __restrict__ out, int n)
{
    __shared__ float Ws[64][68];
    __shared__ float P[WPB][4][64];
    __shared__ float rowbuf[WPB][64];
    int tid = threadIdx.x;
    for (int idx = tid; idx < 4096; idx += 512) Ws[idx >> 6][idx & 63] = W[idx];
    __syncthreads();
    float s = 1.0f + eps[0];
    int lane = tid & 63;
    int w = tid >> 6;
    int l16 = lane & 15;
    int g = lane >> 4;
    int wavesTotal = gridDim.x * WPB;
    for (int i = blockIdx.x * WPB + w; i < n; i += wavesTotal) {
        float4 init = make_float4(0.f, 0.f, 0.f, 0.f);
        if (g == 0) {
            float4 self4 = *(const float4*)&h[(size_t)i * 64 + l16 * 4];
            init = make_float4(s * self4.x, s * self4.y, s * self4.z, s * self4.w);
        }
        int2 be = *(const int2*)&off[i];
        int beg = __builtin_amdgcn_readfirstlane(be.x);
        int end = __builtin_amdgcn_readfirstlane(be.y);
        float4 acc4 = gather_row_f32(h, bucket, beg, end, g, l16, init);
        *(float4*)&P[w][g][l16 * 4] = acc4;
        __builtin_amdgcn_wave_barrier();
        float r0 = P[w][0][lane], r1 = P[w][1][lane];
        float r2 = P[w][2][lane], r3 = P[w][3][lane];
        rowbuf[w][lane] = (r0 + r1) + (r2 + r3);
        __builtin_amdgcn_wave_barrier();
        const float4* wrow = (const float4*)&Ws[lane][0];
        const float4* rrow = (const float4*)&rowbuf[w][0];
        float o = 0.f;
#pragma unroll
        for (int k4 = 0; k4 < 16; ++k4) o += dot4(wrow[k4], rrow[k4]);
        out[(size_t)i * 64 + lane] = fmaxf(o, 0.f);
        __builtin_amdgcn_wave_barrier();
    }
}

__global__ __launch_bounds__(512) void fused_final_csr_kernel(
    const float* __restrict__ h1, const int* __restrict__ off,
    const int* __restrict__ bucket, const float* __restrict__ W1,
    const float* __restrict__ Wm, const float* __restrict__ eps,
    float* __restrict__ out, int n)
{
    __shared__ float W1s[64][68];
    __shared__ float Wms[64][68];
    __shared__ float P[WPB][4][64];
    __shared__ float rowbuf[WPB][64];
    __shared__ float selfbuf[WPB][64];
    int tid = threadIdx.x;
    for (int idx = tid; idx < 4096; idx += 512) {
        W1s[idx >> 6][idx & 63] = W1[idx];
        Wms[idx >> 6][idx & 63] = Wm[idx];
    }
    __syncthreads();
    float s = 1.0f + eps[0];
    int lane = tid & 63;
    int w = tid >> 6;
    int l16 = lane & 15;
    int g = lane >> 4;
    int wavesTotal = gridDim.x * WPB;
    for (int i = blockIdx.x * WPB + w; i < n; i += wavesTotal) {
        float4 init = make_float4(0.f, 0.f, 0.f, 0.f);
        if (g == 0) {
            float4 self4 = *(const float4*)&h1[(size_t)i * 64 + l16 * 4];
            *(float4*)&selfbuf[w][l16 * 4] = self4;
            init = make_float4(s * self4.x, s * self4.y, s * self4.z, s * self4.w);
        }
        int2 be = *(const int2*)&off[i];
        int beg = __builtin_amdgcn_readfirstlane(be.x);
        int end = __builtin_amdgcn_readfirstlane(be.y);
        float4 acc4 = gather_row_f32(h1, bucket, beg, end, g, l16, init);
        *(float4*)&P[w][g][l16 * 4] = acc4;
        __builtin_amdgcn_wave_barrier();
        float r0 = P[w][0][lane], r1 = P[w][1][lane];
        float r2 = P[w][2][lane], r3 = P[w][3][lane];
        rowbuf[w][lane] = (r0 + r1) + (r2 + r3);
        __builtin_amdgcn_wave_barrier();
        const float4* w1row = (const float4*)&W1s[lane][0];
        const float4* wmrow = (const float4*)&Wms[lane][0];
        const float4* rrow  = (const float4*)&rowbuf[w][0];
        const float4* srow  = (const float4*)&selfbuf[w][0];
        float o1 = 0.f, o2 = 0.f;
#pragma unroll
        for (int k4 = 0; k4 < 16; ++k4) {
            o1 += dot4(w1row[k4], rrow[k4]);
            o2 += dot4(wmrow[k4], srow[k4]);
        }
        out[(size_t)i * 64 + lane] = (fmaxf(o1, 0.f) + o2) * 0.5f;
        __builtin_amdgcn_wave_barrier();
    }
}

// ================================================================ tier C: atomic scatter
__global__ __launch_bounds__(256) void init_scale_kernel(
    const float* __restrict__ h, const float* __restrict__ eps,
    float* __restrict__ agg, int total4)
{
    float s = 1.0f + eps[0];
    int i = blockIdx.x * blockDim.x + threadIdx.x;
    int stride = gridDim.x * blockDim.x;
    const float4* h4 = (const float4*)h;
    float4* a4 = (float4*)agg;
    for (; i < total4; i += stride) {
        float4 v = h4[i];
        v.x *= s; v.y *= s; v.z *= s; v.w *= s;
        a4[i] = v;
    }
}

__global__ __launch_bounds__(256) void scatter_kernel(
    const float* __restrict__ h, const int* __restrict__ src,
    const int* __restrict__ dst, float* __restrict__ agg, int E)
{
    int lane = threadIdx.x & 63;
    int e = blockIdx.x * 4 + (threadIdx.x >> 6);
    if (e >= E) return;
    int s = src[e];
    int d = dst[e];
    atomicAdd(&agg[(size_t)d * 64 + lane], h[(size_t)s * 64 + lane]);
}

__global__ __launch_bounds__(256) void gemm_relu_kernel(
    const float* __restrict__ A, const float* __restrict__ W,
    float* __restrict__ out, int n)
{
    __shared__ float Wt[64][65];
    __shared__ float rowbuf[4][64];
    int tid = threadIdx.x;
    for (int i = tid; i < 4096; i += 256) Wt[i & 63][i >> 6] = W[i];
    __syncthreads();
    int lane = tid & 63;
    int w = tid >> 6;
    int wavesTotal = gridDim.x * 4;
    for (int i = blockIdx.x * 4 + w; i < n; i += wavesTotal) {
        rowbuf[w][lane] = A[(size_t)i * 64 + lane];
        __builtin_amdgcn_wave_barrier();
        float o = 0.f;
#pragma unroll
        for (int k = 0; k < 64; ++k) o += rowbuf[w][k] * Wt[k][lane];
        out[(size_t)i * 64 + lane] = fmaxf(o, 0.f);
        __builtin_amdgcn_wave_barrier();
    }
}

__global__ __launch_bounds__(256) void final_kernel(
    const float* __restrict__ Agg, const float* __restrict__ H1,
    const float* __restrict__ W1, const float* __restrict__ Wm,
    float* __restrict__ out, int n)
{
    __shared__ float W1t[64][65];
    __shared__ float Wmt[64][65];
    __shared__ float rowbuf[4][64];
    __shared__ float selfbuf[4][64];
    int tid = threadIdx.x;
    for (int i = tid; i < 4096; i += 256) {
        W1t[i & 63][i >> 6] = W1[i];
        Wmt[i & 63][i >> 6] = Wm[i];
    }
    __syncthreads();
    int lane = tid & 63;
    int w = tid >> 6;
    int wavesTotal = gridDim.x * 4;
    for (int i = blockIdx.x * 4 + w; i < n; i += wavesTotal) {
        rowbuf[w][lane] = Agg[(size_t)i * 64 + lane];
        selfbuf[w][lane] = H1[(size_t)i * 64 + lane];
        __builtin_amdgcn_wave_barrier();
        float o1 = 0.f, o2 = 0.f;
#pragma unroll
        for (int k = 0; k < 64; ++k) {
            o1 += rowbuf[w][k] * W1t[k][lane];
            o2 += selfbuf[w][k] * Wmt[k][lane];
        }
        out[(size_t)i * 64 + lane] = (fmaxf(o1, 0.f) + o2) * 0.5f;
        __builtin_amdgcn_wave_barrier();
    }
}

// ================================================================ launch
extern "C" void kernel_launch(void* const* d_in, const int* in_sizes, int n_in,
                              void* d_out, int out_size, void* d_ws, size_t ws_size,
                              hipStream_t stream)
{
    const float* x    = (const float*)d_in[0];
    const int*   ei   = (const int*)d_in[1];
    const float* W0   = (const float*)d_in[2];
    const float* eps0 = (const float*)d_in[3];
    const float* W1   = (const float*)d_in[4];
    const float* eps1 = (const float*)d_in[5];
    const float* Wm   = (const float*)d_in[6];
    float* out = (float*)d_out;

    int n = in_sizes[0] / 64;   // 100000
    int E = in_sizes[1] / 2;    // 1600000
    const int* src = ei;
    const int* dst = ei + E;

    auto align1k = [](size_t v) { return (v + 1023) & ~(size_t)1023; };

    // ---- tier A layout (fp16 mirrors; ~39.3 MB)
    size_t hhx_off    = 0;
    size_t hh1_off    = align1k(hhx_off + (size_t)n * 64 * 2);
    size_t off_off    = align1k(hh1_off + (size_t)n * 64 * 2);
    size_t deg_off    = align1k(off_off + (size_t)(n + 1) * 4);
    size_t bsum_off   = align1k(deg_off + (size_t)n * 4);
    size_t bucket_off = align1k(bsum_off + 256 * 4);
    size_t rank_off   = align1k(bucket_off + (size_t)(E + 64) * 4);
    size_t need_A2    = rank_off + (size_t)E * 4;

    // ---- tier B layout (fp32, cursor fill; ~33.2 MB)
    size_t b_h1_off     = 0;
    size_t b_off_off    = align1k(b_h1_off + (size_t)n * 64 * 4);
    size_t b_deg_off    = align1k(b_off_off + (size_t)(n + 1) * 4);
    size_t b_cursor_off = align1k(b_deg_off + (size_t)n * 4);
    size_t b_bsum_off   = align1k(b_cursor_off + (size_t)n * 4);
    size_t b_bucket_off = align1k(b_bsum_off + 256 * 4);
    size_t need_B       = b_bucket_off + (size_t)E * 4;

    int nb = (n + 1023) / 1024;            // <=256 required
    int e8Blocks  = (E + 2047) / 2048;
    int e16Blocks = (E + 4095) / 4096;
    int total4 = n * 16;

    if (ws_size >= need_A2) {
        __half* hhx  = (__half*)((char*)d_ws + hhx_off);
        __half* hh1  = (__half*)((char*)d_ws + hh1_off);
        int* off     = (int*)((char*)d_ws + off_off);
        int* deg     = (int*)((char*)d_ws + deg_off);
        int* bsum    = (int*)((char*)d_ws + bsum_off);
        int* bucket  = (int*)((char*)d_ws + bucket_off);
        int* rank    = (int*)((char*)d_ws + rank_off);

        zero_convert_kernel<<<2048, 256, 0, stream>>>(deg, n, x, hhx, total4);
        hist_rank_kernel<<<e16Blocks, 256, 0, stream>>>(dst, deg, rank, E);
        scanA_kernel<<<nb, 256, 0, stream>>>(deg, off, bsum, n);
        scanB_kernel<<<1, 256, 0, stream>>>(bsum, nb);
        scanC_kernel<<<nb, 256, 0, stream>>>(off, (int*)nullptr, bsum, n, E);
        fill_rank_kernel<<<e8Blocks, 256, 0, stream>>>(src, dst, rank, off, bucket, E);

        // grid 2048 = 8 blocks/CU queued (cap 4 resident): HW rebalances tail
        fused_gin_h_kernel<<<2048, 512, 0, stream>>>(hhx, off, bucket, W0, eps0, hh1, n);
        fused_final_h_kernel<<<2048, 512, 0, stream>>>(hh1, off, bucket, W1, Wm, eps1, out, n);
    } else if (ws_size >= need_B) {
        float* h1    = (float*)((char*)d_ws + b_h1_off);
        int* off     = (int*)((char*)d_ws + b_off_off);
        int* deg     = (int*)((char*)d_ws + b_deg_off);
        int* cursor  = (int*)((char*)d_ws + b_cursor_off);
        int* bsum    = (int*)((char*)d_ws + b_bsum_off);
        int* bucket  = (int*)((char*)d_ws + b_bucket_off);

        zero_int_kernel<<<256, 256, 0, stream>>>(deg, n);
        hist_kernel<<<(E + 1023) / 1024, 256, 0, stream>>>(dst, deg, E);
        scanA_kernel<<<nb, 256, 0, stream>>>(deg, off, bsum, n);
        scanB_kernel<<<1, 256, 0, stream>>>(bsum, nb);
        scanC_kernel<<<nb, 256, 0, stream>>>(off, cursor, bsum, n, E);
        fill_kernel<<<(E + 255) / 256, 256, 0, stream>>>(src, dst, cursor, bucket, E);

        fused_gin_kernel<<<1024, 512, 0, stream>>>(x, off, bucket, W0, eps0, h1, n);
        fused_final_csr_kernel<<<768, 512, 0, stream>>>(h1, off, bucket, W1, Wm, eps1, out, n);
    } else {
        float* agg = (float*)d_ws;
        float* h1  = out;
        int scatterBlocks = (E + 3) / 4;

        init_scale_kernel<<<2048, 256, 0, stream>>>(x, eps0, agg, total4);
        scatter_kernel<<<scatterBlocks, 256, 0, stream>>>(x, src, dst, agg, E);
        gemm_relu_kernel<<<2048, 256, 0, stream>>>(agg, W0, h1, n);
        init_scale_kernel<<<2048, 256, 0, stream>>>(h1, eps1, agg, total4);
        scatter_kernel<<<scatterBlocks, 256, 0, stream>>>(h1, src, dst, agg, E);
        final_kernel<<<2048, 256, 0, stream>>>(agg, h1, W1, Wm, out, n);
    }
}